// Round 18
// baseline (218.509 us; speedup 1.0000x reference)
//
#include <hip/hip_runtime.h>
#include <cstdint>

#define B_   32
#define C_   512
#define N_   1024
#define G_   32
#define CG_  16

typedef unsigned short u16;
typedef unsigned char u8;
typedef unsigned long long u64;

static constexpr float kEps = 1e-5f;
// 512^-0.5 * log2(e): softmax computed base-2 (exp2), base-change invariant.
static constexpr float kLog2Scale = 0.06375871752987579f;

using f32x4  = __attribute__((ext_vector_type(4))) float;
using short8 = __attribute__((ext_vector_type(8))) short;
using i64x2  = __attribute__((ext_vector_type(2))) long long;

__device__ __forceinline__ u16 f2bf(float f) {
  uint32_t u = __builtin_bit_cast(uint32_t, f);
  u += 0x7fffu + ((u >> 16) & 1u);   // RNE
  return (u16)(u >> 16);
}
__device__ __forceinline__ float bf2f(u16 h) {
  return __builtin_bit_cast(float, (uint32_t)h << 16);
}
// pack 4 f32 -> 4 fp8 e4m3 bytes
__device__ __forceinline__ int pk4_fp8(float a, float b, float c, float d) {
  int w = __builtin_amdgcn_cvt_pk_fp8_f32(a, b, 0, false);
  w = __builtin_amdgcn_cvt_pk_fp8_f32(c, d, w, true);
  return w;
}
// K-interleaved fp8 byte position: within each 64-k tile, 16B chunk j holds
// logical 8B blocks {j, j+4}  ->  ds_read_b128 gives one lane kk0+kk1 operands.
__device__ __forceinline__ int f8pos(int k) {
  const int c8 = (k >> 3) & 7;
  return (k & ~63) + ((c8 & 3) << 4) + ((c8 >> 2) << 3) + (k & 4);
}

// async global->LDS, 16B per lane. LDS dest is wave-uniform base (HW adds lane*16).
__device__ __forceinline__ void gload16(const void* g, void* lds) {
  __builtin_amdgcn_global_load_lds(
      (__attribute__((address_space(1))) void*)(uintptr_t)g,
      (__attribute__((address_space(3))) void*)(uint32_t)(uintptr_t)lds,
      16, 0, 0);
}

// bijective XCD-chunked remap (m204).
__device__ __forceinline__ uint3 remap_xcd() {
  const int gx = gridDim.x, gy = gridDim.y, gz = gridDim.z;
  const int nwg = gx * gy * gz;
  const int lin = blockIdx.x + gx * (blockIdx.y + gy * blockIdx.z);
  const int q = nwg >> 3, r = nwg & 7;
  const int xcd = lin & 7, pos = lin >> 3;
  int nid = (xcd < r ? xcd * (q + 1) : r * (q + 1) + (xcd - r) * q) + pos;
  uint3 o;
  o.x = nid % gx; nid /= gx;
  o.y = nid % gy; o.z = nid / gy;
  return o;
}

// ---------------- fp32->bf16 weight converts: Wq->Wab[0], Wk->Wbb[0], Wv->Wab[1] ----
__global__ __launch_bounds__(256) void wcvt_kernel(
    const float* __restrict__ Wq, const float* __restrict__ Wk,
    const float* __restrict__ Wv, u16* __restrict__ Wab, u16* __restrict__ Wbb) {
  const int idx = blockIdx.x * 256 + threadIdx.x;     // 3*65536 float4s
  const int src = idx >> 16;
  const int e = (idx & 65535) * 4;
  const float* W = (src == 0) ? Wq : (src == 1) ? Wk : Wv;
  u16* D = (src == 0) ? Wab : (src == 1) ? Wbb : (Wab + 262144);
  const float4 v = *(const float4*)(W + e);
  ushort4 st;
  st.x = f2bf(v.x); st.y = f2bf(v.y); st.z = f2bf(v.z); st.w = f2bf(v.w);
  *(ushort4*)(D + e) = st;
}

// ---------------- Wn transpose: Wbb[1][o][c'] = bf16(Wn[c'][o]) ----------------
__global__ __launch_bounds__(256) void wtr_kernel(
    const float* __restrict__ Wn, u16* __restrict__ Wtn) {
  __shared__ float tile[64][65];
  const int c0 = blockIdx.y * 64, o0 = blockIdx.x * 64;
  const int tx = threadIdx.x & 15, ty = threadIdx.x >> 4;
#pragma unroll
  for (int rr = 0; rr < 64; rr += 16) {
    const int c = c0 + ty + rr;
    const float4 v = *(const float4*)(Wn + (size_t)c * 512 + o0 + tx * 4);
    tile[ty + rr][tx * 4 + 0] = v.x;
    tile[ty + rr][tx * 4 + 1] = v.y;
    tile[ty + rr][tx * 4 + 2] = v.z;
    tile[ty + rr][tx * 4 + 3] = v.w;
  }
  __syncthreads();
#pragma unroll
  for (int rr = 0; rr < 64; rr += 16) {
    const int o = o0 + ty + rr;
    ushort4 st;
    st.x = f2bf(tile[tx * 4 + 0][ty + rr]);
    st.y = f2bf(tile[tx * 4 + 1][ty + rr]);
    st.z = f2bf(tile[tx * 4 + 2][ty + rr]);
    st.w = f2bf(tile[tx * 4 + 3][ty + rr]);
    *(ushort4*)(Wtn + (size_t)o * 512 + c0 + tx * 4) = st;
  }
}

// ---------------- bias vectors: wkbq[d] = Wk[d]·bq ; bvn[o] = bv·Wn[:,o] + bn[o] ------
__global__ __launch_bounds__(512) void biask_kernel(
    const float* __restrict__ Wk, const float* __restrict__ bq,
    const float* __restrict__ Wn, const float* __restrict__ bv,
    const float* __restrict__ bn, float* __restrict__ wkbq,
    float* __restrict__ bvn) {
  const int t = threadIdx.x;
  if (blockIdx.x == 0) {
    float s = 0.f;
    const float* row = Wk + (size_t)t * 512;
    for (int o = 0; o < 512; ++o) s += row[o] * bq[o];
    wkbq[t] = s;
  } else {
    float s = 0.f;
    for (int c = 0; c < 512; ++c) s += bv[c] * Wn[(size_t)c * 512 + t];
    bvn[t] = s + bn[t];
  }
}

// ---------------- fused groupnorm: bf16 LDS stage (33KB -> 4 blocks/CU), fp8 outputs ----
__global__ __launch_bounds__(256) void gn_fused(const float* __restrict__ x,
                                                u8* __restrict__ Hn8,
                                                u8* __restrict__ HnT8) {
  __shared__ u16 lds2[16 * 1032];
  __shared__ float red[10];
  const int bg = blockIdx.x, b = bg >> 5, g = bg & 31;
  const int t = threadIdx.x;
  const float4* p4 = (const float4*)(x + (size_t)bg * 16384);
  float s = 0.f, s2 = 0.f;
  for (int i = t; i < 4096; i += 256) {
    const float4 v = p4[i];
    const int e = i * 4, ic = e >> 10, n = e & 1023;
    ushort4 sv;
    sv.x = f2bf(v.x); sv.y = f2bf(v.y); sv.z = f2bf(v.z); sv.w = f2bf(v.w);
    *(ushort4*)(lds2 + ic * 1032 + n) = sv;
    s  += v.x + v.y + v.z + v.w;
    s2 += v.x * v.x + v.y * v.y + v.z * v.z + v.w * v.w;
  }
#pragma unroll
  for (int o = 32; o; o >>= 1) { s += __shfl_xor(s, o); s2 += __shfl_xor(s2, o); }
  const int lane = t & 63, w = t >> 6;
  if (lane == 0) { red[w] = s; red[4 + w] = s2; }
  __syncthreads();
  if (t == 0) {
    s  = red[0] + red[1] + red[2] + red[3];
    s2 = red[4] + red[5] + red[6] + red[7];
    const float inv = 1.0f / 16384.0f;
    const float mean = s * inv;
    const float var  = s2 * inv - mean * mean;
    red[8] = mean;
    red[9] = rsqrtf(var + kEps);
  }
  __syncthreads();
  const float mean = red[8], rstd = red[9];
#pragma unroll
  for (int r = 0; r < 4; ++r) {
    const int n = t + 256 * r;
    float vals[16];
#pragma unroll
    for (int ic = 0; ic < 16; ++ic)
      vals[ic] = (bf2f(lds2[ic * 1032 + n]) - mean) * rstd;
    const u64 lo = (u64)(uint32_t)pk4_fp8(vals[0], vals[1], vals[2], vals[3]) |
                   ((u64)(uint32_t)pk4_fp8(vals[4], vals[5], vals[6], vals[7]) << 32);
    const u64 hi = (u64)(uint32_t)pk4_fp8(vals[8], vals[9], vals[10], vals[11]) |
                   ((u64)(uint32_t)pk4_fp8(vals[12], vals[13], vals[14], vals[15]) << 32);
    u8* rb = Hn8 + ((size_t)(b * N_ + n)) * C_;
    *(u64*)(rb + f8pos(g * 16))     = lo;
    *(u64*)(rb + f8pos(g * 16 + 8)) = hi;
  }
  // HnT8[c][n] interleaved over k=n: each thread packs 4 consecutive n
  const int nb = t * 4;
#pragma unroll
  for (int ic = 0; ic < 16; ++ic) {
    const ushort4 hv = *(const ushort4*)(lds2 + ic * 1032 + nb);
    const int wv = pk4_fp8((bf2f(hv.x) - mean) * rstd, (bf2f(hv.y) - mean) * rstd,
                           (bf2f(hv.z) - mean) * rstd, (bf2f(hv.w) - mean) * rstd);
    *(int*)(HnT8 + ((size_t)(b * C_ + g * 16 + ic)) * N_ + f8pos(nb)) = wv;
  }
}

// ---------------- light 128x128 bf16 GEMM -> fp8 interleaved weight products ----------
__global__ __launch_bounds__(256) void gemm_w128(
    const u16* __restrict__ Ab, const u16* __restrict__ Bb, u8* __restrict__ Ob) {
  __shared__ u16 Alds[128 * 64];
  __shared__ u16 Blds[128 * 64];
  const int p = blockIdx.z;
  const u16* A = Ab + (size_t)p * 262144;
  const u16* B = Bb + (size_t)p * 262144;
  u8* O = Ob + (size_t)p * 262144;
  const int m0 = blockIdx.y * 128, n0 = blockIdx.x * 128;
  const int tid = threadIdx.x, lane = tid & 63, wid = tid >> 6;
  const int wm = wid >> 1, wn = wid & 1;
  const int sr = lane >> 3, scb = (lane & 7) ^ sr;
  const u16* Ag = A + (size_t)(m0 + wid * 32 + sr) * 512 + scb * 8;
  const u16* Bg = B + (size_t)(n0 + wid * 32 + sr) * 512 + scb * 8;
  char* Al = (char*)Alds + wid * 4096;
  char* Bl = (char*)Blds + wid * 4096;
  const int arow = lane & 15, g4 = lane >> 4, rx = lane & 7;
  f32x4 acc[4][4] = {};
  for (int k = 0; k < 512; k += 64) {
#pragma unroll
    for (int g = 0; g < 4; ++g) {
      gload16(Ag + k + g * (8 * 512), Al + g * 1024);
      gload16(Bg + k + g * (8 * 512), Bl + g * 1024);
    }
    __syncthreads();
#pragma unroll
    for (int kk = 0; kk < 2; ++kk) {
      const int pc = ((kk * 4 + g4) ^ rx) * 16;
      short8 a[4], b[4];
#pragma unroll
      for (int i = 0; i < 4; ++i)
        a[i] = *(const short8*)((const char*)Alds + (wm * 64 + i * 16 + arow) * 128 + pc);
#pragma unroll
      for (int j = 0; j < 4; ++j)
        b[j] = *(const short8*)((const char*)Blds + (wn * 64 + j * 16 + arow) * 128 + pc);
#pragma unroll
      for (int i = 0; i < 4; ++i)
#pragma unroll
        for (int j = 0; j < 4; ++j)
          acc[i][j] = __builtin_amdgcn_mfma_f32_16x16x32_bf16(a[i], b[j], acc[i][j], 0, 0, 0);
    }
    __syncthreads();
  }
#pragma unroll
  for (int i = 0; i < 4; ++i) {
    const int rowg = m0 + wm * 64 + i * 16 + ((lane >> 4) * 4);   // k-axis (c)
#pragma unroll
    for (int j = 0; j < 4; ++j) {
      const int colg = n0 + wn * 64 + j * 16 + (lane & 15);       // row (d or o)
      const f32x4 v = acc[i][j];
      *(int*)(O + (size_t)colg * 512 + f8pos(rowg)) =
          pk4_fp8(v[0], v[1], v[2], v[3]);
    }
  }
}

// ================= fp8 256x256 core: K-interleaved layout, b128 fragment reads ======
#define LDA8_(D, BASE, MH)                                                      \
  _Pragma("unroll")                                                             \
  for (int i_ = 0; i_ < 4; ++i_) {                                              \
    const int rr_ = wm * 128 + (MH) * 64 + i_ * 16 + arow;                      \
    D[i_] = *(const i64x2*)((BASE) + rr_ * 64 +                                 \
                            ((g4 ^ ((rr_ >> 1) & 3)) << 4));                    \
  }
#define LDB8_(D, BASE)                                                          \
  _Pragma("unroll")                                                             \
  for (int j_ = 0; j_ < 4; ++j_) {                                              \
    const int rr_ = wn * 64 + j_ * 16 + arow;                                   \
    D[j_] = *(const i64x2*)((BASE) + rr_ * 64 +                                 \
                            ((g4 ^ ((rr_ >> 1) & 3)) << 4));                    \
  }
#define LDB8J2_(D, BASE)                                                        \
  _Pragma("unroll")                                                             \
  for (int j_ = 0; j_ < 2; ++j_) {                                              \
    const int rr_ = wn * 32 + j_ * 16 + arow;                                   \
    D[j_] = *(const i64x2*)((BASE) + rr_ * 64 +                                 \
                            ((g4 ^ ((rr_ >> 1) & 3)) << 4));                    \
  }
#define MM8_(ACC, AA, BB, H)                                                    \
  __builtin_amdgcn_s_setprio(1);                                                \
  _Pragma("unroll")                                                             \
  for (int i_ = 0; i_ < 4; ++i_)                                                \
    _Pragma("unroll")                                                           \
    for (int j_ = 0; j_ < 4; ++j_)                                              \
      ACC[i_][j_] = __builtin_amdgcn_mfma_f32_16x16x32_fp8_fp8(                 \
          AA[i_][H], BB[j_][H], ACC[i_][j_], 0, 0, 0);                          \
  __builtin_amdgcn_s_setprio(0);
#define MM8J2_(ACC, AA, BB, H)                                                  \
  __builtin_amdgcn_s_setprio(1);                                                \
  _Pragma("unroll")                                                             \
  for (int i_ = 0; i_ < 4; ++i_)                                                \
    _Pragma("unroll")                                                           \
    for (int j_ = 0; j_ < 2; ++j_)                                              \
      ACC[i_][j_] = __builtin_amdgcn_mfma_f32_16x16x32_fp8_fp8(                 \
          AA[i_][H], BB[j_][H], ACC[i_][j_], 0, 0, 0);                          \
  __builtin_amdgcn_s_setprio(0);

__device__ __forceinline__ void gemm_core256_f8(
    const u8* __restrict__ A, const u8* __restrict__ B,
    int Ktot, int m0, int n0,
    char* Alds, char* Blds, f32x4 acc0[4][4], f32x4 acc1[4][4]) {
  const int tid = threadIdx.x, lane = tid & 63, wid = tid >> 6;
  const int wm = wid >> 2, wn = wid & 3;
  const int rl = lane >> 2;
  const int c16 = (lane & 3) ^ ((lane >> 3) & 3);   // pre-swizzled source 16B chunk
  const u8* Ag = A + (size_t)(m0 + wid * 32 + rl) * Ktot + c16 * 16;
  const u8* Bg = B + (size_t)(n0 + wid * 32 + rl) * Ktot + c16 * 16;
  char* Al = Alds + wid * 2048;
  char* Bl = Blds + wid * 2048;
  const long long r16 = (long long)16 * Ktot;
  const int arow = lane & 15, g4 = lane >> 4;
  const int nt = Ktot >> 6;

#pragma unroll
  for (int g = 0; g < 2; ++g) {
    gload16(Ag + g * r16, Al + g * 1024);
    gload16(Bg + g * r16, Bl + g * 1024);
  }
  asm volatile("s_waitcnt vmcnt(0)" ::: "memory");
  __builtin_amdgcn_s_barrier();
  i64x2 aX[4], aY[4], bX[4];
  LDA8_(aX, Alds, 0);

  for (int t = 0; t < nt; ++t) {
    const int cur = t & 1;
    const char* Ab = Alds + cur * 16384;
    const char* Bb = Blds + cur * 16384;
    const char* An = Alds + (cur ^ 1) * 16384;
    char* Aln = Al + (cur ^ 1) * 16384;
    char* Bln = Bl + (cur ^ 1) * 16384;
    const bool nx = (t + 1 < nt);
    const long long ko = (long long)(t + 1) * 64;

    // ph0: stage next-B ; read bX + aY(mh1) ; MFMA(acc0, aX.kk0, bX.kk0)
    if (nx) {
#pragma unroll
      for (int g = 0; g < 2; ++g) gload16(Bg + ko + g * r16, Bln + g * 1024);
    }
    LDB8_(bX, Bb);
    LDA8_(aY, Ab, 1);
    asm volatile("s_waitcnt lgkmcnt(4)" ::: "memory");   // bX done; aY in flight
    __builtin_amdgcn_sched_barrier(0);
    __builtin_amdgcn_s_barrier();
    MM8_(acc0, aX, bX, 0);

    // ph1: stage next-A ; MFMA(acc1, aY.kk0, bX.kk0)
    if (nx) {
#pragma unroll
      for (int g = 0; g < 2; ++g) gload16(Ag + ko + g * r16, Aln + g * 1024);
    }
    asm volatile("s_waitcnt lgkmcnt(0)" ::: "memory");   // aY done
    __builtin_amdgcn_sched_barrier(0);
    __builtin_amdgcn_s_barrier();
    MM8_(acc1, aY, bX, 0);

    // ph2: MFMA(acc0, aX.kk1, bX.kk1)
    __builtin_amdgcn_sched_barrier(0);
    __builtin_amdgcn_s_barrier();
    MM8_(acc0, aX, bX, 1);

    // ph3: boundary; prefetch next aX under MFMA(acc1, aY.kk1, bX.kk1)
    if (nx) {
      asm volatile("s_waitcnt vmcnt(0)" ::: "memory");   // own stage loads landed
    }
    __builtin_amdgcn_sched_barrier(0);
    __builtin_amdgcn_s_barrier();                        // all waves: stages landed
    if (nx) {
      LDA8_(aX, An, 0);
    }
    MM8_(acc1, aY, bX, 1);
  }
}

// coalesced copy-out of a 256x256B fp8 tile staged in SH (row stride 256B, row-XOR swz).
__device__ __forceinline__ void copy_out_tile(const char* SH, u8* O, int LDC,
                                              int m0, int n0) {
  const int tid = threadIdx.x;
#pragma unroll
  for (int it = 0; it < 8; ++it) {
    const int flat = it * 8192 + tid * 16;
    const int row = flat >> 8, col = flat & 255;
    *(int4*)(O + (size_t)(n0 + row) * LDC + m0 + col) =
        *(const int4*)(SH + row * 256 + (col ^ ((row & 15) << 4)));
  }
}

// HWq8[n][d] = fp8(Hn·Wqk + wkbq), interleaved over d. A=WqkT8 rows d, B=Hn8 rows n.
__global__ __launch_bounds__(512, 2) void gemm_hwq_f8(
    const u8* __restrict__ Wqk8, const u8* __restrict__ Hn8,
    const float* __restrict__ wkbq, u8* __restrict__ HWq8) {
  __shared__ char SH[4 * 256 * 64];    // core: A | B halves; epilogue: 256x256B tile
  const uint3 bid = remap_xcd();
  const int z = bid.z;
  const u8* B = Hn8 + (size_t)z * ((size_t)N_ * C_);
  u8* O = HWq8 + (size_t)z * ((size_t)N_ * C_);
  const int m0 = bid.y * 256, n0 = bid.x * 256;   // m0: d, n0: n
  f32x4 acc0[4][4] = {};
  f32x4 acc1[4][4] = {};
  gemm_core256_f8(Wqk8, B, 512, m0, n0, SH, SH + 32768, acc0, acc1);

  const int lane = threadIdx.x & 63, wid = threadIdx.x >> 6;
  const int wm = wid >> 2, wn = wid & 3;
  __syncthreads();
#pragma unroll
  for (int i = 0; i < 8; ++i) {
    const int ml = wm * 128 + i * 16 + ((lane >> 4) * 4);          // d local
    const float4 bv = *(const float4*)(wkbq + m0 + ml);
    const int fp = f8pos(ml);
#pragma unroll
    for (int j = 0; j < 4; ++j) {
      const int nl = wn * 64 + j * 16 + (lane & 15);               // n local
      const f32x4 v = (i < 4) ? acc0[i][j] : acc1[i - 4][j];
      *(int*)(SH + nl * 256 + (fp ^ ((nl & 15) << 4))) =
          pk4_fp8(v[0] + bv.x, v[1] + bv.y, v[2] + bv.z, v[3] + bv.w);
    }
  }
  __syncthreads();
  copy_out_tile(SH, O, 512, m0, n0);
}

// S + exp2 epilogue: A=Hn8 rows m, B=HWq8 rows n, K=512.
__global__ __launch_bounds__(512, 2) void gemm_s_f8(
    const u8* __restrict__ Hn8, const u8* __restrict__ HWq8,
    u8* __restrict__ P8, float* __restrict__ Psum) {
  __shared__ char SH[4 * 256 * 64];
  const uint3 bid = remap_xcd();
  const int z = bid.z;
  const u8* A = Hn8  + (size_t)z * ((size_t)N_ * C_);
  const u8* B = HWq8 + (size_t)z * ((size_t)N_ * C_);
  u8*       O = P8   + (size_t)z * ((size_t)N_ * N_);
  const int m0 = bid.y * 256, n0 = bid.x * 256;
  f32x4 acc0[4][4] = {};
  f32x4 acc1[4][4] = {};
  gemm_core256_f8(A, B, 512, m0, n0, SH, SH + 32768, acc0, acc1);

  const int lane = threadIdx.x & 63, wid = threadIdx.x >> 6;
  const int wm = wid >> 2, wn = wid & 3;
  float psum[4] = {0.f, 0.f, 0.f, 0.f};
  __syncthreads();
#pragma unroll
  for (int i = 0; i < 8; ++i) {
    const int ml = wm * 128 + i * 16 + ((lane >> 4) * 4);          // m local
    const int fp = f8pos(ml);
#pragma unroll
    for (int j = 0; j < 4; ++j) {
      const int nl = wn * 64 + j * 16 + (lane & 15);               // n local
      const f32x4 v = (i < 4) ? acc0[i][j] : acc1[i - 4][j];
      const float p0 = __builtin_exp2f(v[0] * kLog2Scale) * 0.0625f;
      const float p1 = __builtin_exp2f(v[1] * kLog2Scale) * 0.0625f;
      const float p2 = __builtin_exp2f(v[2] * kLog2Scale) * 0.0625f;
      const float p3 = __builtin_exp2f(v[3] * kLog2Scale) * 0.0625f;
      psum[j] += (p0 + p1) + (p2 + p3);
      *(int*)(SH + nl * 256 + (fp ^ ((nl & 15) << 4))) = pk4_fp8(p0, p1, p2, p3);
    }
  }
  const int slot = (m0 >> 7) + wm;             // 0..7, one wave per slot
  float* Ps = Psum + ((size_t)z * 8 + slot) * N_;
#pragma unroll
  for (int j = 0; j < 4; ++j) {
    float r = psum[j];
    r += __shfl_xor(r, 16);
    r += __shfl_xor(r, 32);
    if (lane < 16) Ps[n0 + wn * 64 + j * 16 + lane] = r;
  }
  __syncthreads();
  copy_out_tile(SH, O, 1024, m0, n0);
}

// ===== fused PV + final, 64-n tiles (512 blocks -> TRUE 2 blocks/CU), 72KB LDS:
//   phase A (PV): H2[n:64][c:512] = softmax-row(P8)·Hn -> swizzled LDS (aliases Abuf)
//   phase B (final): out[o][n] = x + H2·WvWn + bvn  (A from H2-LDS, B=Wvn8 direct L2)
__global__ __launch_bounds__(512, 2) void gemm_pvf_f8(
    const u8* __restrict__ HnT8, const u8* __restrict__ P8,
    const float* __restrict__ Psum, const u8* __restrict__ Wvn8,
    const float* __restrict__ x, const float* __restrict__ bvn,
    float* __restrict__ Out) {
  __shared__ char SH[73728];    // [0,64K) A dbuf 2x32K (H2 32K aliases); [64K,72K) B dbuf
  char* Abuf = SH;
  char* Bbuf = SH + 65536;
  char* H2   = SH;              // 64 rows x 512B, chunk-swizzled; written after K-loop
  const uint3 bid = remap_xcd();
  const int z = bid.z;
  const u8* A = HnT8 + (size_t)z * ((size_t)N_ * C_);   // rows c (512), ld 1024
  const u8* B = P8   + (size_t)z * ((size_t)N_ * N_);   // rows n, ld 1024
  const int n0 = bid.x * 64;
  const int tid = threadIdx.x, lane = tid & 63, wid = tid >> 6;
  const int wm = wid >> 1, wn = wid & 1;                // PV: 4M(c) x 2N(n)
  const int rl = lane >> 2;
  const int c16 = (lane & 3) ^ ((lane >> 3) & 3);
  const u8* Ag = A + (size_t)(wid * 64 + rl) * 1024 + c16 * 16;
  const u8* Bg = B + (size_t)(n0 + wid * 16 + rl) * 1024 + c16 * 16;  // waves 0-3 only
  const int arow = lane & 15, g4 = lane >> 4;
  f32x4 acc0[4][2] = {};
  f32x4 acc1[4][2] = {};

  // prologue: stage tile 0 (A: 4 gloads x 16 rows per wave; B: waves 0-3, 1 gload)
#pragma unroll
  for (int g = 0; g < 4; ++g)
    gload16(Ag + (size_t)g * (16 * 1024), Abuf + wid * 4096 + g * 1024);
  if (wid < 4) gload16(Bg, Bbuf + wid * 1024);
  asm volatile("s_waitcnt vmcnt(0)" ::: "memory");
  __builtin_amdgcn_s_barrier();
  i64x2 aX[4], aY[4], bX[2];
  LDA8_(aX, Abuf, 0);

  for (int t = 0; t < 16; ++t) {
    const int cur = t & 1;
    const char* Ab = Abuf + cur * 32768;
    const char* Bb = Bbuf + cur * 4096;
    const char* An = Abuf + (cur ^ 1) * 32768;
    const bool nx = (t + 1 < 16);
    const long long ko = (long long)(t + 1) * 64;

    // ph0: stage next-B (waves 0-3) ; read bX + aY(mh1) ; MFMA kk0 mh0
    if (nx && wid < 4) gload16(Bg + ko, Bbuf + (cur ^ 1) * 4096 + wid * 1024);
    LDB8J2_(bX, Bb);
    LDA8_(aY, Ab, 1);
    asm volatile("s_waitcnt lgkmcnt(4)" ::: "memory");   // bX done; aY in flight
    __builtin_amdgcn_sched_barrier(0);
    __builtin_amdgcn_s_barrier();
    MM8J2_(acc0, aX, bX, 0);

    // ph1: stage next-A(4) ; MFMA kk0 mh1
    if (nx) {
#pragma unroll
      for (int g = 0; g < 4; ++g)
        gload16(Ag + ko + (size_t)g * (16 * 1024),
                Abuf + (cur ^ 1) * 32768 + wid * 4096 + g * 1024);
    }
    asm volatile("s_waitcnt lgkmcnt(0)" ::: "memory");
    __builtin_amdgcn_sched_barrier(0);
    __builtin_amdgcn_s_barrier();
    MM8J2_(acc1, aY, bX, 0);

    // ph2: MFMA kk1 mh0
    __builtin_amdgcn_sched_barrier(0);
    __builtin_amdgcn_s_barrier();
    MM8J2_(acc0, aX, bX, 1);

    // ph3: boundary; next aX under MFMA kk1 mh1
    if (nx) {
      asm volatile("s_waitcnt vmcnt(0)" ::: "memory");
    }
    __builtin_amdgcn_sched_barrier(0);
    __builtin_amdgcn_s_barrier();
    if (nx) {
      LDA8_(aX, An, 0);
    }
    MM8J2_(acc1, aY, bX, 1);
  }
  __syncthreads();   // all A/B ds_reads done in all waves -> safe to overwrite Abuf (H2)

  // --- PV epilogue: normalize, store H2 tile to LDS (chunk-swizzled) ---
  const float* Ps = Psum + (size_t)z * 8 * N_;
  float inv[2];
#pragma unroll
  for (int j = 0; j < 2; ++j) {
    const int ng = n0 + wn * 32 + j * 16 + (lane & 15);
    float s = 0.f;
#pragma unroll
    for (int k = 0; k < 8; ++k) s += Ps[k * N_ + ng];
    inv[j] = 1.0f / s;
  }
#pragma unroll
  for (int i = 0; i < 8; ++i) {
    const int c = wm * 128 + i * 16 + ((lane >> 4) * 4);           // c in [0,512)
    const int fp = f8pos(c);
    const int ck = fp >> 4, sub = fp & 15;
#pragma unroll
    for (int j = 0; j < 2; ++j) {
      const int nl = wn * 32 + j * 16 + (lane & 15);               // n local [0,64)
      const f32x4 v = (i < 4) ? acc0[i][j] : acc1[i - 4][j];
      *(int*)(H2 + nl * 512 + ((ck ^ (nl & 15)) << 4) + sub) =
          pk4_fp8(v[0] * inv[j], v[1] * inv[j], v[2] * inv[j], v[3] * inv[j]);
    }
  }
  __syncthreads();

  // --- final phase: out[o][n] = x + H2·WvWn + bvn; A=H2(LDS rows n), B=Wvn8(L2 rows o)
  const int wmf = wid >> 2, wnf = wid & 3;   // 2M(n: 2x32) x 4N(o: 4x128)
  f32x4 acc2[2][8] = {};
#pragma unroll
  for (int t = 0; t < 8; ++t) {
    i64x2 a2[2], b2[8];
#pragma unroll
    for (int i = 0; i < 2; ++i) {
      const int rn = wmf * 32 + i * 16 + arow;
      a2[i] = *(const i64x2*)(H2 + rn * 512 + (((t * 4 + g4) ^ (rn & 15)) << 4));
    }
#pragma unroll
    for (int j = 0; j < 8; ++j) {
      const int ro = wnf * 128 + j * 16 + arow;
      b2[j] = *(const i64x2*)(Wvn8 + (size_t)ro * 512 + t * 64 + g4 * 16);
    }
#pragma unroll
    for (int i = 0; i < 2; ++i)
#pragma unroll
      for (int j = 0; j < 8; ++j)
        acc2[i][j] = __builtin_amdgcn_mfma_f32_16x16x32_fp8_fp8(
            a2[i][0], b2[j][0], acc2[i][j], 0, 0, 0);
#pragma unroll
    for (int i = 0; i < 2; ++i)
#pragma unroll
      for (int j = 0; j < 8; ++j)
        acc2[i][j] = __builtin_amdgcn_mfma_f32_16x16x32_fp8_fp8(
            a2[i][1], b2[j][1], acc2[i][j], 0, 0, 0);
  }

  const float* xb = x + (size_t)z * ((size_t)C_ * N_);
  float* Ob = Out + (size_t)z * ((size_t)C_ * N_);
#pragma unroll
  for (int i = 0; i < 2; ++i) {
    const int rown = n0 + wmf * 32 + i * 16 + ((lane >> 4) * 4);   // n global
#pragma unroll
    for (int j = 0; j < 8; ++j) {
      const int colo = wnf * 128 + j * 16 + (lane & 15);           // o in [0,512)
      const float bc = bvn[colo];
      const size_t off = (size_t)colo * N_ + rown;
      const float4 xv = *(const float4*)(xb + off);
      const f32x4 v = acc2[i][j];
      float4 ov;
      ov.x = xv.x + v[0] + bc;
      ov.y = xv.y + v[1] + bc;
      ov.z = xv.z + v[2] + bc;
      ov.w = xv.w + v[3] + bc;
      *(float4*)(Ob + off) = ov;
    }
  }
}

__global__ void sentinel_kernel(float* out, int n, float v) {
  const int i = blockIdx.x * blockDim.x + threadIdx.x;
  if (i < n) out[i] = v;
}

extern "C" void kernel_launch(void* const* d_in, const int* in_sizes, int n_in,
                              void* d_out, int out_size, void* d_ws, size_t ws_size,
                              hipStream_t stream) {
  const float* x  = (const float*)d_in[0];
  const float* Wq = (const float*)d_in[1];
  const float* bq = (const float*)d_in[2];
  const float* Wk = (const float*)d_in[3];
  // d_in[4] = bk: drops exactly (softmax shift-invariance over the m axis)
  const float* Wv = (const float*)d_in[5];
  const float* bv = (const float*)d_in[6];
  const float* Wn = (const float*)d_in[7];
  const float* bn = (const float*)d_in[8];
  float* out = (float*)d_out;

  char* ws = (char*)d_ws;
  size_t off = 0;
  u16* Wab = (u16*)(ws + off); off += (size_t)2 * 262144 * 2;  // bf16: Wq | Wv
  u16* Wbb = (u16*)(ws + off); off += (size_t)2 * 262144 * 2;  // bf16: Wk | WnT
  u8*  W8  = (u8*)(ws + off);  off += (size_t)2 * 262144;      // fp8: WqkT8 | WvWnT8
  float* wkbq = (float*)(ws + off); off += 512 * 4;
  float* bvn  = (float*)(ws + off); off += 512 * 4;
  const size_t bnc = (size_t)B_ * N_ * C_;
  u8* Hn8  = (u8*)(ws + off); off += bnc;               // fp8 [b][n][c] interleaved
  u8* HnT8 = (u8*)(ws + off); off += bnc;               // fp8 [b][c][n] interleaved
  u8* HWq8 = (u8*)(ws + off); off += bnc;               // fp8 [b][n][d] interleaved
  u8* P8   = (u8*)(ws + off); off += (size_t)B_ * N_ * N_;  // fp8 [b][n][m] interleaved
  float* Psum = (float*)(ws + off); off += (size_t)B_ * 8 * N_ * 4;

  if (ws_size < off) {
    const float v = 1.0e6f + (float)(ws_size >> 20);   // absmax ~ 1e6+MB -> diagnosable
    sentinel_kernel<<<(out_size + 255) / 256, 256, 0, stream>>>(out, out_size, v);
    return;
  }

  // weight prep
  wcvt_kernel<<<768, 256, 0, stream>>>(Wq, Wk, Wv, Wab, Wbb);
  wtr_kernel<<<dim3(8, 8), 256, 0, stream>>>(Wn, Wbb + 262144);
  biask_kernel<<<2, 512, 0, stream>>>(Wk, bq, Wn, bv, bn, wkbq, bvn);
  // groupnorm -> fp8 interleaved Hn8 / HnT8
  gn_fused<<<B_ * G_, 256, 0, stream>>>(x, Hn8, HnT8);
  // weight products -> fp8 interleaved
  gemm_w128<<<dim3(4, 4, 2), 256, 0, stream>>>(Wab, Wbb, W8);
  // HWq8[n][d] = fp8(Hn·Wqk + wkbq)
  gemm_hwq_f8<<<dim3(4, 2, B_), 512, 0, stream>>>(W8, Hn8, wkbq, HWq8);
  // P8[n][m] = fp8(exp2(scale·(HWq[n]·Hn[m]))/16) + partial row-sums
  gemm_s_f8<<<dim3(4, 4, B_), 512, 0, stream>>>(Hn8, HWq8, P8, Psum);
  // fused PV + final (64-n tiles, 512 blocks -> 2 blocks/CU)
  gemm_pvf_f8<<<dim3(16, 1, B_), 512, 0, stream>>>(HnT8, P8, Psum, W8 + 262144, x, bvn, out);
}

// Round 19
// 192.820 us; speedup vs baseline: 1.1332x; 1.1332x over previous
//
#include <hip/hip_runtime.h>
#include <cstdint>

#define B_   32
#define C_   512
#define N_   1024
#define G_   32
#define CG_  16

typedef unsigned short u16;
typedef unsigned char u8;
typedef unsigned long long u64;

static constexpr float kEps = 1e-5f;
// 512^-0.5 * log2(e): softmax computed base-2 (exp2), base-change invariant.
static constexpr float kLog2Scale = 0.06375871752987579f;

using f32x4  = __attribute__((ext_vector_type(4))) float;
using short8 = __attribute__((ext_vector_type(8))) short;
using i64x2  = __attribute__((ext_vector_type(2))) long long;

__device__ __forceinline__ u16 f2bf(float f) {
  uint32_t u = __builtin_bit_cast(uint32_t, f);
  u += 0x7fffu + ((u >> 16) & 1u);   // RNE
  return (u16)(u >> 16);
}
__device__ __forceinline__ float bf2f(u16 h) {
  return __builtin_bit_cast(float, (uint32_t)h << 16);
}
// pack 4 f32 -> 4 fp8 e4m3 bytes
__device__ __forceinline__ int pk4_fp8(float a, float b, float c, float d) {
  int w = __builtin_amdgcn_cvt_pk_fp8_f32(a, b, 0, false);
  w = __builtin_amdgcn_cvt_pk_fp8_f32(c, d, w, true);
  return w;
}
// K-interleaved fp8 byte position: within each 64-k tile, 16B chunk j holds
// logical 8B blocks {j, j+4}  ->  ds_read_b128 gives one lane kk0+kk1 operands.
__device__ __forceinline__ int f8pos(int k) {
  const int c8 = (k >> 3) & 7;
  return (k & ~63) + ((c8 & 3) << 4) + ((c8 >> 2) << 3) + (k & 4);
}

// async global->LDS, 16B per lane. LDS dest is wave-uniform base (HW adds lane*16).
__device__ __forceinline__ void gload16(const void* g, void* lds) {
  __builtin_amdgcn_global_load_lds(
      (__attribute__((address_space(1))) void*)(uintptr_t)g,
      (__attribute__((address_space(3))) void*)(uint32_t)(uintptr_t)lds,
      16, 0, 0);
}

// bijective XCD-chunked remap (m204).
__device__ __forceinline__ uint3 remap_xcd() {
  const int gx = gridDim.x, gy = gridDim.y, gz = gridDim.z;
  const int nwg = gx * gy * gz;
  const int lin = blockIdx.x + gx * (blockIdx.y + gy * blockIdx.z);
  const int q = nwg >> 3, r = nwg & 7;
  const int xcd = lin & 7, pos = lin >> 3;
  int nid = (xcd < r ? xcd * (q + 1) : r * (q + 1) + (xcd - r) * q) + pos;
  uint3 o;
  o.x = nid % gx; nid /= gx;
  o.y = nid % gy; o.z = nid / gy;
  return o;
}

// ---------------- fp32->bf16 weight converts: Wq->Wab[0], Wk->Wbb[0], Wv->Wab[1] ----
__global__ __launch_bounds__(256) void wcvt_kernel(
    const float* __restrict__ Wq, const float* __restrict__ Wk,
    const float* __restrict__ Wv, u16* __restrict__ Wab, u16* __restrict__ Wbb) {
  const int idx = blockIdx.x * 256 + threadIdx.x;     // 3*65536 float4s
  const int src = idx >> 16;
  const int e = (idx & 65535) * 4;
  const float* W = (src == 0) ? Wq : (src == 1) ? Wk : Wv;
  u16* D = (src == 0) ? Wab : (src == 1) ? Wbb : (Wab + 262144);
  const float4 v = *(const float4*)(W + e);
  ushort4 st;
  st.x = f2bf(v.x); st.y = f2bf(v.y); st.z = f2bf(v.z); st.w = f2bf(v.w);
  *(ushort4*)(D + e) = st;
}

// ---------------- Wn transpose: Wbb[1][o][c'] = bf16(Wn[c'][o]) ----------------
__global__ __launch_bounds__(256) void wtr_kernel(
    const float* __restrict__ Wn, u16* __restrict__ Wtn) {
  __shared__ float tile[64][65];
  const int c0 = blockIdx.y * 64, o0 = blockIdx.x * 64;
  const int tx = threadIdx.x & 15, ty = threadIdx.x >> 4;
#pragma unroll
  for (int rr = 0; rr < 64; rr += 16) {
    const int c = c0 + ty + rr;
    const float4 v = *(const float4*)(Wn + (size_t)c * 512 + o0 + tx * 4);
    tile[ty + rr][tx * 4 + 0] = v.x;
    tile[ty + rr][tx * 4 + 1] = v.y;
    tile[ty + rr][tx * 4 + 2] = v.z;
    tile[ty + rr][tx * 4 + 3] = v.w;
  }
  __syncthreads();
#pragma unroll
  for (int rr = 0; rr < 64; rr += 16) {
    const int o = o0 + ty + rr;
    ushort4 st;
    st.x = f2bf(tile[tx * 4 + 0][ty + rr]);
    st.y = f2bf(tile[tx * 4 + 1][ty + rr]);
    st.z = f2bf(tile[tx * 4 + 2][ty + rr]);
    st.w = f2bf(tile[tx * 4 + 3][ty + rr]);
    *(ushort4*)(Wtn + (size_t)o * 512 + c0 + tx * 4) = st;
  }
}

// ---------------- bias vectors: wkbq[d] = Wk[d]·bq ; bvn[o] = bv·Wn[:,o] + bn[o] ------
__global__ __launch_bounds__(512) void biask_kernel(
    const float* __restrict__ Wk, const float* __restrict__ bq,
    const float* __restrict__ Wn, const float* __restrict__ bv,
    const float* __restrict__ bn, float* __restrict__ wkbq,
    float* __restrict__ bvn) {
  const int t = threadIdx.x;
  if (blockIdx.x == 0) {
    float s = 0.f;
    const float* row = Wk + (size_t)t * 512;
    for (int o = 0; o < 512; ++o) s += row[o] * bq[o];
    wkbq[t] = s;
  } else {
    float s = 0.f;
    for (int c = 0; c < 512; ++c) s += bv[c] * Wn[(size_t)c * 512 + t];
    bvn[t] = s + bn[t];
  }
}

// ---------------- fused groupnorm: bf16 LDS stage (33KB -> 4 blocks/CU), fp8 outputs ----
__global__ __launch_bounds__(256) void gn_fused(const float* __restrict__ x,
                                                u8* __restrict__ Hn8,
                                                u8* __restrict__ HnT8) {
  __shared__ u16 lds2[16 * 1032];
  __shared__ float red[10];
  const int bg = blockIdx.x, b = bg >> 5, g = bg & 31;
  const int t = threadIdx.x;
  const float4* p4 = (const float4*)(x + (size_t)bg * 16384);
  float s = 0.f, s2 = 0.f;
  for (int i = t; i < 4096; i += 256) {
    const float4 v = p4[i];
    const int e = i * 4, ic = e >> 10, n = e & 1023;
    ushort4 sv;
    sv.x = f2bf(v.x); sv.y = f2bf(v.y); sv.z = f2bf(v.z); sv.w = f2bf(v.w);
    *(ushort4*)(lds2 + ic * 1032 + n) = sv;
    s  += v.x + v.y + v.z + v.w;
    s2 += v.x * v.x + v.y * v.y + v.z * v.z + v.w * v.w;
  }
#pragma unroll
  for (int o = 32; o; o >>= 1) { s += __shfl_xor(s, o); s2 += __shfl_xor(s2, o); }
  const int lane = t & 63, w = t >> 6;
  if (lane == 0) { red[w] = s; red[4 + w] = s2; }
  __syncthreads();
  if (t == 0) {
    s  = red[0] + red[1] + red[2] + red[3];
    s2 = red[4] + red[5] + red[6] + red[7];
    const float inv = 1.0f / 16384.0f;
    const float mean = s * inv;
    const float var  = s2 * inv - mean * mean;
    red[8] = mean;
    red[9] = rsqrtf(var + kEps);
  }
  __syncthreads();
  const float mean = red[8], rstd = red[9];
#pragma unroll
  for (int r = 0; r < 4; ++r) {
    const int n = t + 256 * r;
    float vals[16];
#pragma unroll
    for (int ic = 0; ic < 16; ++ic)
      vals[ic] = (bf2f(lds2[ic * 1032 + n]) - mean) * rstd;
    const u64 lo = (u64)(uint32_t)pk4_fp8(vals[0], vals[1], vals[2], vals[3]) |
                   ((u64)(uint32_t)pk4_fp8(vals[4], vals[5], vals[6], vals[7]) << 32);
    const u64 hi = (u64)(uint32_t)pk4_fp8(vals[8], vals[9], vals[10], vals[11]) |
                   ((u64)(uint32_t)pk4_fp8(vals[12], vals[13], vals[14], vals[15]) << 32);
    u8* rb = Hn8 + ((size_t)(b * N_ + n)) * C_;
    *(u64*)(rb + f8pos(g * 16))     = lo;
    *(u64*)(rb + f8pos(g * 16 + 8)) = hi;
  }
  // HnT8[c][n] interleaved over k=n: each thread packs 4 consecutive n
  const int nb = t * 4;
#pragma unroll
  for (int ic = 0; ic < 16; ++ic) {
    const ushort4 hv = *(const ushort4*)(lds2 + ic * 1032 + nb);
    const int wv = pk4_fp8((bf2f(hv.x) - mean) * rstd, (bf2f(hv.y) - mean) * rstd,
                           (bf2f(hv.z) - mean) * rstd, (bf2f(hv.w) - mean) * rstd);
    *(int*)(HnT8 + ((size_t)(b * C_ + g * 16 + ic)) * N_ + f8pos(nb)) = wv;
  }
}

// ---------------- light 128x128 bf16 GEMM -> fp8 interleaved weight products ----------
__global__ __launch_bounds__(256) void gemm_w128(
    const u16* __restrict__ Ab, const u16* __restrict__ Bb, u8* __restrict__ Ob) {
  __shared__ u16 Alds[128 * 64];
  __shared__ u16 Blds[128 * 64];
  const int p = blockIdx.z;
  const u16* A = Ab + (size_t)p * 262144;
  const u16* B = Bb + (size_t)p * 262144;
  u8* O = Ob + (size_t)p * 262144;
  const int m0 = blockIdx.y * 128, n0 = blockIdx.x * 128;
  const int tid = threadIdx.x, lane = tid & 63, wid = tid >> 6;
  const int wm = wid >> 1, wn = wid & 1;
  const int sr = lane >> 3, scb = (lane & 7) ^ sr;
  const u16* Ag = A + (size_t)(m0 + wid * 32 + sr) * 512 + scb * 8;
  const u16* Bg = B + (size_t)(n0 + wid * 32 + sr) * 512 + scb * 8;
  char* Al = (char*)Alds + wid * 4096;
  char* Bl = (char*)Blds + wid * 4096;
  const int arow = lane & 15, g4 = lane >> 4, rx = lane & 7;
  f32x4 acc[4][4] = {};
  for (int k = 0; k < 512; k += 64) {
#pragma unroll
    for (int g = 0; g < 4; ++g) {
      gload16(Ag + k + g * (8 * 512), Al + g * 1024);
      gload16(Bg + k + g * (8 * 512), Bl + g * 1024);
    }
    __syncthreads();
#pragma unroll
    for (int kk = 0; kk < 2; ++kk) {
      const int pc = ((kk * 4 + g4) ^ rx) * 16;
      short8 a[4], b[4];
#pragma unroll
      for (int i = 0; i < 4; ++i)
        a[i] = *(const short8*)((const char*)Alds + (wm * 64 + i * 16 + arow) * 128 + pc);
#pragma unroll
      for (int j = 0; j < 4; ++j)
        b[j] = *(const short8*)((const char*)Blds + (wn * 64 + j * 16 + arow) * 128 + pc);
#pragma unroll
      for (int i = 0; i < 4; ++i)
#pragma unroll
        for (int j = 0; j < 4; ++j)
          acc[i][j] = __builtin_amdgcn_mfma_f32_16x16x32_bf16(a[i], b[j], acc[i][j], 0, 0, 0);
    }
    __syncthreads();
  }
#pragma unroll
  for (int i = 0; i < 4; ++i) {
    const int rowg = m0 + wm * 64 + i * 16 + ((lane >> 4) * 4);   // k-axis (c)
#pragma unroll
    for (int j = 0; j < 4; ++j) {
      const int colg = n0 + wn * 64 + j * 16 + (lane & 15);       // row (d or o)
      const f32x4 v = acc[i][j];
      *(int*)(O + (size_t)colg * 512 + f8pos(rowg)) =
          pk4_fp8(v[0], v[1], v[2], v[3]);
    }
  }
}

// ================= fp8 256x256 core: K-interleaved layout, b128 fragment reads ======
#define LDA8_(D, BASE, MH)                                                      \
  _Pragma("unroll")                                                             \
  for (int i_ = 0; i_ < 4; ++i_) {                                              \
    const int rr_ = wm * 128 + (MH) * 64 + i_ * 16 + arow;                      \
    D[i_] = *(const i64x2*)((BASE) + rr_ * 64 +                                 \
                            ((g4 ^ ((rr_ >> 1) & 3)) << 4));                    \
  }
#define LDB8_(D, BASE)                                                          \
  _Pragma("unroll")                                                             \
  for (int j_ = 0; j_ < 4; ++j_) {                                              \
    const int rr_ = wn * 64 + j_ * 16 + arow;                                   \
    D[j_] = *(const i64x2*)((BASE) + rr_ * 64 +                                 \
                            ((g4 ^ ((rr_ >> 1) & 3)) << 4));                    \
  }
#define MM8_(ACC, AA, BB, H)                                                    \
  __builtin_amdgcn_s_setprio(1);                                                \
  _Pragma("unroll")                                                             \
  for (int i_ = 0; i_ < 4; ++i_)                                                \
    _Pragma("unroll")                                                           \
    for (int j_ = 0; j_ < 4; ++j_)                                              \
      ACC[i_][j_] = __builtin_amdgcn_mfma_f32_16x16x32_fp8_fp8(                 \
          AA[i_][H], BB[j_][H], ACC[i_][j_], 0, 0, 0);                          \
  __builtin_amdgcn_s_setprio(0);

__device__ __forceinline__ void gemm_core256_f8(
    const u8* __restrict__ A, const u8* __restrict__ B,
    int Ktot, int m0, int n0,
    char* Alds, char* Blds, f32x4 acc0[4][4], f32x4 acc1[4][4]) {
  const int tid = threadIdx.x, lane = tid & 63, wid = tid >> 6;
  const int wm = wid >> 2, wn = wid & 3;
  const int rl = lane >> 2;
  const int c16 = (lane & 3) ^ ((lane >> 3) & 3);   // pre-swizzled source 16B chunk
  const u8* Ag = A + (size_t)(m0 + wid * 32 + rl) * Ktot + c16 * 16;
  const u8* Bg = B + (size_t)(n0 + wid * 32 + rl) * Ktot + c16 * 16;
  char* Al = Alds + wid * 2048;
  char* Bl = Blds + wid * 2048;
  const long long r16 = (long long)16 * Ktot;
  const int arow = lane & 15, g4 = lane >> 4;
  const int nt = Ktot >> 6;

#pragma unroll
  for (int g = 0; g < 2; ++g) {
    gload16(Ag + g * r16, Al + g * 1024);
    gload16(Bg + g * r16, Bl + g * 1024);
  }
  asm volatile("s_waitcnt vmcnt(0)" ::: "memory");
  __builtin_amdgcn_s_barrier();
  i64x2 aX[4], aY[4], bX[4];
  LDA8_(aX, Alds, 0);

  for (int t = 0; t < nt; ++t) {
    const int cur = t & 1;
    const char* Ab = Alds + cur * 16384;
    const char* Bb = Blds + cur * 16384;
    const char* An = Alds + (cur ^ 1) * 16384;
    char* Aln = Al + (cur ^ 1) * 16384;
    char* Bln = Bl + (cur ^ 1) * 16384;
    const bool nx = (t + 1 < nt);
    const long long ko = (long long)(t + 1) * 64;

    // ph0: stage next-B ; read bX + aY(mh1) ; MFMA(acc0, aX.kk0, bX.kk0)
    if (nx) {
#pragma unroll
      for (int g = 0; g < 2; ++g) gload16(Bg + ko + g * r16, Bln + g * 1024);
    }
    LDB8_(bX, Bb);
    LDA8_(aY, Ab, 1);
    asm volatile("s_waitcnt lgkmcnt(4)" ::: "memory");   // bX done; aY in flight
    __builtin_amdgcn_sched_barrier(0);
    __builtin_amdgcn_s_barrier();
    MM8_(acc0, aX, bX, 0);

    // ph1: stage next-A ; MFMA(acc1, aY.kk0, bX.kk0)
    if (nx) {
#pragma unroll
      for (int g = 0; g < 2; ++g) gload16(Ag + ko + g * r16, Aln + g * 1024);
    }
    asm volatile("s_waitcnt lgkmcnt(0)" ::: "memory");   // aY done
    __builtin_amdgcn_sched_barrier(0);
    __builtin_amdgcn_s_barrier();
    MM8_(acc1, aY, bX, 0);

    // ph2: MFMA(acc0, aX.kk1, bX.kk1)
    __builtin_amdgcn_sched_barrier(0);
    __builtin_amdgcn_s_barrier();
    MM8_(acc0, aX, bX, 1);

    // ph3: boundary; prefetch next aX under MFMA(acc1, aY.kk1, bX.kk1)
    if (nx) {
      asm volatile("s_waitcnt vmcnt(0)" ::: "memory");   // own stage loads landed
    }
    __builtin_amdgcn_sched_barrier(0);
    __builtin_amdgcn_s_barrier();                        // all waves: stages landed
    if (nx) {
      LDA8_(aX, An, 0);
    }
    MM8_(acc1, aY, bX, 1);
  }
}

// coalesced copy-out of a 256x256B fp8 tile staged in SH (row stride 256B, row-XOR swz).
__device__ __forceinline__ void copy_out_tile(const char* SH, u8* O, int LDC,
                                              int m0, int n0) {
  const int tid = threadIdx.x;
#pragma unroll
  for (int it = 0; it < 8; ++it) {
    const int flat = it * 8192 + tid * 16;
    const int row = flat >> 8, col = flat & 255;
    *(int4*)(O + (size_t)(n0 + row) * LDC + m0 + col) =
        *(const int4*)(SH + row * 256 + (col ^ ((row & 15) << 4)));
  }
}

// HWq8[n][d] = fp8(Hn·Wqk + wkbq), interleaved over d. A=WqkT8 rows d, B=Hn8 rows n.
__global__ __launch_bounds__(512, 2) void gemm_hwq_f8(
    const u8* __restrict__ Wqk8, const u8* __restrict__ Hn8,
    const float* __restrict__ wkbq, u8* __restrict__ HWq8) {
  __shared__ char SH[4 * 256 * 64];    // core: A | B halves; epilogue: 256x256B tile
  const uint3 bid = remap_xcd();
  const int z = bid.z;
  const u8* B = Hn8 + (size_t)z * ((size_t)N_ * C_);
  u8* O = HWq8 + (size_t)z * ((size_t)N_ * C_);
  const int m0 = bid.y * 256, n0 = bid.x * 256;   // m0: d, n0: n
  f32x4 acc0[4][4] = {};
  f32x4 acc1[4][4] = {};
  gemm_core256_f8(Wqk8, B, 512, m0, n0, SH, SH + 32768, acc0, acc1);

  const int lane = threadIdx.x & 63, wid = threadIdx.x >> 6;
  const int wm = wid >> 2, wn = wid & 3;
  __syncthreads();
#pragma unroll
  for (int i = 0; i < 8; ++i) {
    const int ml = wm * 128 + i * 16 + ((lane >> 4) * 4);          // d local
    const float4 bv = *(const float4*)(wkbq + m0 + ml);
    const int fp = f8pos(ml);
#pragma unroll
    for (int j = 0; j < 4; ++j) {
      const int nl = wn * 64 + j * 16 + (lane & 15);               // n local
      const f32x4 v = (i < 4) ? acc0[i][j] : acc1[i - 4][j];
      *(int*)(SH + nl * 256 + (fp ^ ((nl & 15) << 4))) =
          pk4_fp8(v[0] + bv.x, v[1] + bv.y, v[2] + bv.z, v[3] + bv.w);
    }
  }
  __syncthreads();
  copy_out_tile(SH, O, 512, m0, n0);
}

// S + exp2 epilogue: A=Hn8 rows m, B=HWq8 rows n, K=512.
__global__ __launch_bounds__(512, 2) void gemm_s_f8(
    const u8* __restrict__ Hn8, const u8* __restrict__ HWq8,
    u8* __restrict__ P8, float* __restrict__ Psum) {
  __shared__ char SH[4 * 256 * 64];
  const uint3 bid = remap_xcd();
  const int z = bid.z;
  const u8* A = Hn8  + (size_t)z * ((size_t)N_ * C_);
  const u8* B = HWq8 + (size_t)z * ((size_t)N_ * C_);
  u8*       O = P8   + (size_t)z * ((size_t)N_ * N_);
  const int m0 = bid.y * 256, n0 = bid.x * 256;
  f32x4 acc0[4][4] = {};
  f32x4 acc1[4][4] = {};
  gemm_core256_f8(A, B, 512, m0, n0, SH, SH + 32768, acc0, acc1);

  const int lane = threadIdx.x & 63, wid = threadIdx.x >> 6;
  const int wm = wid >> 2, wn = wid & 3;
  float psum[4] = {0.f, 0.f, 0.f, 0.f};
  __syncthreads();
#pragma unroll
  for (int i = 0; i < 8; ++i) {
    const int ml = wm * 128 + i * 16 + ((lane >> 4) * 4);          // m local
    const int fp = f8pos(ml);
#pragma unroll
    for (int j = 0; j < 4; ++j) {
      const int nl = wn * 64 + j * 16 + (lane & 15);               // n local
      const f32x4 v = (i < 4) ? acc0[i][j] : acc1[i - 4][j];
      const float p0 = __builtin_exp2f(v[0] * kLog2Scale) * 0.0625f;
      const float p1 = __builtin_exp2f(v[1] * kLog2Scale) * 0.0625f;
      const float p2 = __builtin_exp2f(v[2] * kLog2Scale) * 0.0625f;
      const float p3 = __builtin_exp2f(v[3] * kLog2Scale) * 0.0625f;
      psum[j] += (p0 + p1) + (p2 + p3);
      *(int*)(SH + nl * 256 + (fp ^ ((nl & 15) << 4))) = pk4_fp8(p0, p1, p2, p3);
    }
  }
  const int slot = (m0 >> 7) + wm;             // 0..7, one wave per slot
  float* Ps = Psum + ((size_t)z * 8 + slot) * N_;
#pragma unroll
  for (int j = 0; j < 4; ++j) {
    float r = psum[j];
    r += __shfl_xor(r, 16);
    r += __shfl_xor(r, 32);
    if (lane < 16) Ps[n0 + wn * 64 + j * 16 + lane] = r;
  }
  __syncthreads();
  copy_out_tile(SH, O, 1024, m0, n0);
}

// ===== fused PV + final: per block (z, 128-n-tile):
//   phase A (PV): H2[n:128][c:512] = softmax-row(P8)·Hn  -> swizzled LDS tile
//   phase B (final): out[o][n] = x + H2·WvWn + bvn  (A-frags from H2-LDS, B direct L2)
__global__ __launch_bounds__(512, 1) void gemm_pvf_f8(
    const u8* __restrict__ HnT8, const u8* __restrict__ P8,
    const float* __restrict__ Psum, const u8* __restrict__ Wvn8,
    const float* __restrict__ x, const float* __restrict__ bvn,
    float* __restrict__ Out) {
  __shared__ char SH[147456];   // [0,64K) A dbuf 2x32K; [64K,80K) B dbuf 2x8K; [80K,144K) H2
  char* Abuf = SH;
  char* Bbuf = SH + 65536;
  char* H2   = SH + 81920;      // 128 rows x 512B, chunk-swizzled
  const uint3 bid = remap_xcd();
  const int z = bid.z;
  const u8* A = HnT8 + (size_t)z * ((size_t)N_ * C_);   // rows c (512), ld 1024
  const u8* B = P8   + (size_t)z * ((size_t)N_ * N_);   // rows n, ld 1024
  const int n0 = bid.x * 128;
  const int tid = threadIdx.x, lane = tid & 63, wid = tid >> 6;
  const int wm = wid >> 1, wn = wid & 1;                // PV: 4M(c) x 2N(n)
  const int rl = lane >> 2;
  const int c16 = (lane & 3) ^ ((lane >> 3) & 3);
  const u8* Ag = A + (size_t)(wid * 64 + rl) * 1024 + c16 * 16;
  const u8* Bg = B + (size_t)(n0 + wid * 16 + rl) * 1024 + c16 * 16;
  const int arow = lane & 15, g4 = lane >> 4;
  f32x4 acc0[4][4] = {};
  f32x4 acc1[4][4] = {};

  // prologue: stage tile 0 (A: 4 gloads of 16 rows; B: 1 gload)
#pragma unroll
  for (int g = 0; g < 4; ++g)
    gload16(Ag + (size_t)g * (16 * 1024), Abuf + wid * 4096 + g * 1024);
  gload16(Bg, Bbuf + wid * 1024);
  asm volatile("s_waitcnt vmcnt(0)" ::: "memory");
  __builtin_amdgcn_s_barrier();
  i64x2 aX[4], aY[4], bX[4];
  LDA8_(aX, Abuf, 0);

  for (int t = 0; t < 16; ++t) {
    const int cur = t & 1;
    const char* Ab = Abuf + cur * 32768;
    const char* Bb = Bbuf + cur * 8192;
    const char* An = Abuf + (cur ^ 1) * 32768;
    const bool nx = (t + 1 < 16);
    const long long ko = (long long)(t + 1) * 64;

    // ph0: stage next-B(1) ; read bX + aY(mh1) ; MFMA kk0 mh0
    if (nx) gload16(Bg + ko, Bbuf + (cur ^ 1) * 8192 + wid * 1024);
    LDB8_(bX, Bb);
    LDA8_(aY, Ab, 1);
    asm volatile("s_waitcnt lgkmcnt(4)" ::: "memory");
    __builtin_amdgcn_sched_barrier(0);
    __builtin_amdgcn_s_barrier();
    MM8_(acc0, aX, bX, 0);

    // ph1: stage next-A(4) ; MFMA kk0 mh1
    if (nx) {
#pragma unroll
      for (int g = 0; g < 4; ++g)
        gload16(Ag + ko + (size_t)g * (16 * 1024),
                Abuf + (cur ^ 1) * 32768 + wid * 4096 + g * 1024);
    }
    asm volatile("s_waitcnt lgkmcnt(0)" ::: "memory");
    __builtin_amdgcn_sched_barrier(0);
    __builtin_amdgcn_s_barrier();
    MM8_(acc1, aY, bX, 0);

    // ph2: MFMA kk1 mh0
    __builtin_amdgcn_sched_barrier(0);
    __builtin_amdgcn_s_barrier();
    MM8_(acc0, aX, bX, 1);

    // ph3: boundary; next aX under MFMA kk1 mh1
    if (nx) {
      asm volatile("s_waitcnt vmcnt(0)" ::: "memory");
    }
    __builtin_amdgcn_sched_barrier(0);
    __builtin_amdgcn_s_barrier();
    if (nx) {
      LDA8_(aX, An, 0);
    }
    MM8_(acc1, aY, bX, 1);
  }

  // --- PV epilogue: normalize, store H2 tile to LDS (chunk-swizzled) ---
  const float* Ps = Psum + (size_t)z * 8 * N_;
  float inv[4];
#pragma unroll
  for (int j = 0; j < 4; ++j) {
    const int ng = n0 + wn * 64 + j * 16 + (lane & 15);
    float s = 0.f;
#pragma unroll
    for (int k = 0; k < 8; ++k) s += Ps[k * N_ + ng];
    inv[j] = 1.0f / s;
  }
#pragma unroll
  for (int i = 0; i < 8; ++i) {
    const int c = wm * 128 + i * 16 + ((lane >> 4) * 4);           // c in [0,512)
    const int fp = f8pos(c);
    const int ck = fp >> 4, sub = fp & 15;
#pragma unroll
    for (int j = 0; j < 4; ++j) {
      const int nl = wn * 64 + j * 16 + (lane & 15);               // n local [0,128)
      const f32x4 v = (i < 4) ? acc0[i][j] : acc1[i - 4][j];
      *(int*)(H2 + nl * 512 + ((ck ^ (nl & 15)) << 4) + sub) =
          pk4_fp8(v[0] * inv[j], v[1] * inv[j], v[2] * inv[j], v[3] * inv[j]);
    }
  }
  __syncthreads();

  // --- final phase: out[o][n] = x + H2·WvWn + bvn; A=H2(LDS rows n), B=Wvn8(L2 rows o)
  const int wmf = wid >> 2, wnf = wid & 3;   // 2M(n) x 4N(o)
  f32x4 acc2[4][8] = {};
#pragma unroll
  for (int t = 0; t < 8; ++t) {
    i64x2 a2[4], b2[8];
#pragma unroll
    for (int i = 0; i < 4; ++i) {
      const int rn = wmf * 64 + i * 16 + arow;
      a2[i] = *(const i64x2*)(H2 + rn * 512 + (((t * 4 + g4) ^ (rn & 15)) << 4));
    }
#pragma unroll
    for (int j = 0; j < 8; ++j) {
      const int ro = wnf * 128 + j * 16 + arow;
      b2[j] = *(const i64x2*)(Wvn8 + (size_t)ro * 512 + t * 64 + g4 * 16);
    }
#pragma unroll
    for (int i = 0; i < 4; ++i)
#pragma unroll
      for (int j = 0; j < 8; ++j)
        acc2[i][j] = __builtin_amdgcn_mfma_f32_16x16x32_fp8_fp8(
            a2[i][0], b2[j][0], acc2[i][j], 0, 0, 0);
#pragma unroll
    for (int i = 0; i < 4; ++i)
#pragma unroll
      for (int j = 0; j < 8; ++j)
        acc2[i][j] = __builtin_amdgcn_mfma_f32_16x16x32_fp8_fp8(
            a2[i][1], b2[j][1], acc2[i][j], 0, 0, 0);
  }

  const float* xb = x + (size_t)z * ((size_t)C_ * N_);
  float* Ob = Out + (size_t)z * ((size_t)C_ * N_);
#pragma unroll
  for (int i = 0; i < 4; ++i) {
    const int rown = n0 + wmf * 64 + i * 16 + ((lane >> 4) * 4);   // n global
#pragma unroll
    for (int j = 0; j < 8; ++j) {
      const int colo = wnf * 128 + j * 16 + (lane & 15);           // o in [0,512)
      const float bc = bvn[colo];
      const size_t off = (size_t)colo * N_ + rown;
      const float4 xv = *(const float4*)(xb + off);
      const f32x4 v = acc2[i][j];
      float4 ov;
      ov.x = xv.x + v[0] + bc;
      ov.y = xv.y + v[1] + bc;
      ov.z = xv.z + v[2] + bc;
      ov.w = xv.w + v[3] + bc;
      *(float4*)(Ob + off) = ov;
    }
  }
}

__global__ void sentinel_kernel(float* out, int n, float v) {
  const int i = blockIdx.x * blockDim.x + threadIdx.x;
  if (i < n) out[i] = v;
}

extern "C" void kernel_launch(void* const* d_in, const int* in_sizes, int n_in,
                              void* d_out, int out_size, void* d_ws, size_t ws_size,
                              hipStream_t stream) {
  const float* x  = (const float*)d_in[0];
  const float* Wq = (const float*)d_in[1];
  const float* bq = (const float*)d_in[2];
  const float* Wk = (const float*)d_in[3];
  // d_in[4] = bk: drops exactly (softmax shift-invariance over the m axis)
  const float* Wv = (const float*)d_in[5];
  const float* bv = (const float*)d_in[6];
  const float* Wn = (const float*)d_in[7];
  const float* bn = (const float*)d_in[8];
  float* out = (float*)d_out;

  char* ws = (char*)d_ws;
  size_t off = 0;
  u16* Wab = (u16*)(ws + off); off += (size_t)2 * 262144 * 2;  // bf16: Wq | Wv
  u16* Wbb = (u16*)(ws + off); off += (size_t)2 * 262144 * 2;  // bf16: Wk | WnT
  u8*  W8  = (u8*)(ws + off);  off += (size_t)2 * 262144;      // fp8: WqkT8 | WvWnT8
  float* wkbq = (float*)(ws + off); off += 512 * 4;
  float* bvn  = (float*)(ws + off); off += 512 * 4;
  const size_t bnc = (size_t)B_ * N_ * C_;
  u8* Hn8  = (u8*)(ws + off); off += bnc;               // fp8 [b][n][c] interleaved
  u8* HnT8 = (u8*)(ws + off); off += bnc;               // fp8 [b][c][n] interleaved
  u8* HWq8 = (u8*)(ws + off); off += bnc;               // fp8 [b][n][d] interleaved
  u8* P8   = (u8*)(ws + off); off += (size_t)B_ * N_ * N_;  // fp8 [b][n][m] interleaved
  float* Psum = (float*)(ws + off); off += (size_t)B_ * 8 * N_ * 4;

  if (ws_size < off) {
    const float v = 1.0e6f + (float)(ws_size >> 20);   // absmax ~ 1e6+MB -> diagnosable
    sentinel_kernel<<<(out_size + 255) / 256, 256, 0, stream>>>(out, out_size, v);
    return;
  }

  // weight prep
  wcvt_kernel<<<768, 256, 0, stream>>>(Wq, Wk, Wv, Wab, Wbb);
  wtr_kernel<<<dim3(8, 8), 256, 0, stream>>>(Wn, Wbb + 262144);
  biask_kernel<<<2, 512, 0, stream>>>(Wk, bq, Wn, bv, bn, wkbq, bvn);
  // groupnorm -> fp8 interleaved Hn8 / HnT8
  gn_fused<<<B_ * G_, 256, 0, stream>>>(x, Hn8, HnT8);
  // weight products -> fp8 interleaved
  gemm_w128<<<dim3(4, 4, 2), 256, 0, stream>>>(Wab, Wbb, W8);
  // HWq8[n][d] = fp8(Hn·Wqk + wkbq)
  gemm_hwq_f8<<<dim3(4, 2, B_), 512, 0, stream>>>(W8, Hn8, wkbq, HWq8);
  // P8[n][m] = fp8(exp2(scale·(HWq[n]·Hn[m]))/16) + partial row-sums
  gemm_s_f8<<<dim3(4, 4, B_), 512, 0, stream>>>(Hn8, HWq8, P8, Psum);
  // fused PV + final: out = x + (softmax(P)·Hn)·WvWn + bvn
  gemm_pvf_f8<<<dim3(8, 1, B_), 512, 0, stream>>>(HnT8, P8, Psum, W8 + 262144, x, bvn, out);
}

// Round 20
// 171.731 us; speedup vs baseline: 1.2724x; 1.1228x over previous
//
#include <hip/hip_runtime.h>
#include <cstdint>

#define B_   32
#define C_   512
#define N_   1024
#define G_   32
#define CG_  16

typedef unsigned short u16;
typedef unsigned char u8;
typedef unsigned long long u64;

static constexpr float kEps = 1e-5f;
// 512^-0.5 * log2(e): softmax computed base-2 (exp2), base-change invariant.
static constexpr float kLog2Scale = 0.06375871752987579f;

using f32x4  = __attribute__((ext_vector_type(4))) float;
using short8 = __attribute__((ext_vector_type(8))) short;
using i64x2  = __attribute__((ext_vector_type(2))) long long;

__device__ __forceinline__ u16 f2bf(float f) {
  uint32_t u = __builtin_bit_cast(uint32_t, f);
  u += 0x7fffu + ((u >> 16) & 1u);   // RNE
  return (u16)(u >> 16);
}
__device__ __forceinline__ float bf2f(u16 h) {
  return __builtin_bit_cast(float, (uint32_t)h << 16);
}
// pack 4 f32 -> 4 fp8 e4m3 bytes
__device__ __forceinline__ int pk4_fp8(float a, float b, float c, float d) {
  int w = __builtin_amdgcn_cvt_pk_fp8_f32(a, b, 0, false);
  w = __builtin_amdgcn_cvt_pk_fp8_f32(c, d, w, true);
  return w;
}
// K-interleaved fp8 byte position: within each 64-k tile, 16B chunk j holds
// logical 8B blocks {j, j+4}  ->  ds_read_b128 gives one lane kk0+kk1 operands.
__device__ __forceinline__ int f8pos(int k) {
  const int c8 = (k >> 3) & 7;
  return (k & ~63) + ((c8 & 3) << 4) + ((c8 >> 2) << 3) + (k & 4);
}

// async global->LDS, 16B per lane. LDS dest is wave-uniform base (HW adds lane*16).
__device__ __forceinline__ void gload16(const void* g, void* lds) {
  __builtin_amdgcn_global_load_lds(
      (__attribute__((address_space(1))) void*)(uintptr_t)g,
      (__attribute__((address_space(3))) void*)(uint32_t)(uintptr_t)lds,
      16, 0, 0);
}

// bijective XCD-chunked remap (m204).
__device__ __forceinline__ uint3 remap_xcd() {
  const int gx = gridDim.x, gy = gridDim.y, gz = gridDim.z;
  const int nwg = gx * gy * gz;
  const int lin = blockIdx.x + gx * (blockIdx.y + gy * blockIdx.z);
  const int q = nwg >> 3, r = nwg & 7;
  const int xcd = lin & 7, pos = lin >> 3;
  int nid = (xcd < r ? xcd * (q + 1) : r * (q + 1) + (xcd - r) * q) + pos;
  uint3 o;
  o.x = nid % gx; nid /= gx;
  o.y = nid % gy; o.z = nid / gy;
  return o;
}

// ---------------- merged prep: fp32->bf16 converts + Wn transpose + bias vectors ------
// blocks [0,768): Wq->Wab[0], Wk->Wbb[0], Wv->Wab[1] (bf16 converts)
// blocks [768,832): Wbb[1][o][c'] = bf16(Wn[c'][o])   (LDS tile transpose)
// blocks [832,836): wkbq[d] = Wk[d]·bq ; bvn[o] = bv·Wn[:,o] + bn[o]
__global__ __launch_bounds__(256) void prep_kernel(
    const float* __restrict__ Wq, const float* __restrict__ Wk,
    const float* __restrict__ Wv, const float* __restrict__ Wn,
    const float* __restrict__ bq, const float* __restrict__ bv,
    const float* __restrict__ bn,
    u16* __restrict__ Wab, u16* __restrict__ Wbb,
    float* __restrict__ wkbq, float* __restrict__ bvn) {
  __shared__ float tile[64][65];
  const int blk = blockIdx.x;
  if (blk < 768) {
    const int idx = blk * 256 + threadIdx.x;          // 3*65536 float4s
    const int src = idx >> 16;
    const int e = (idx & 65535) * 4;
    const float* W = (src == 0) ? Wq : (src == 1) ? Wk : Wv;
    u16* D = (src == 0) ? Wab : (src == 1) ? Wbb : (Wab + 262144);
    const float4 v = *(const float4*)(W + e);
    ushort4 st;
    st.x = f2bf(v.x); st.y = f2bf(v.y); st.z = f2bf(v.z); st.w = f2bf(v.w);
    *(ushort4*)(D + e) = st;
  } else if (blk < 832) {
    const int idx2 = blk - 768;                       // wtr: 8x8 tiles of 64x64
    const int c0 = (idx2 >> 3) * 64, o0 = (idx2 & 7) * 64;
    u16* Wtn = Wbb + 262144;
    const int tx = threadIdx.x & 15, ty = threadIdx.x >> 4;
#pragma unroll
    for (int rr = 0; rr < 64; rr += 16) {
      const int c = c0 + ty + rr;
      const float4 v = *(const float4*)(Wn + (size_t)c * 512 + o0 + tx * 4);
      tile[ty + rr][tx * 4 + 0] = v.x;
      tile[ty + rr][tx * 4 + 1] = v.y;
      tile[ty + rr][tx * 4 + 2] = v.z;
      tile[ty + rr][tx * 4 + 3] = v.w;
    }
    __syncthreads();
#pragma unroll
    for (int rr = 0; rr < 64; rr += 16) {
      const int o = o0 + ty + rr;
      ushort4 st;
      st.x = f2bf(tile[tx * 4 + 0][ty + rr]);
      st.y = f2bf(tile[tx * 4 + 1][ty + rr]);
      st.z = f2bf(tile[tx * 4 + 2][ty + rr]);
      st.w = f2bf(tile[tx * 4 + 3][ty + rr]);
      *(ushort4*)(Wtn + (size_t)o * 512 + c0 + tx * 4) = st;
    }
  } else {
    const int which = blk - 832;                      // 0,1: wkbq halves; 2,3: bvn halves
    const int t = (which & 1) * 256 + threadIdx.x;
    if ((which >> 1) == 0) {
      float s = 0.f;
      const float* row = Wk + (size_t)t * 512;
      for (int o = 0; o < 512; ++o) s += row[o] * bq[o];
      wkbq[t] = s;
    } else {
      float s = 0.f;
      for (int c = 0; c < 512; ++c) s += bv[c] * Wn[(size_t)c * 512 + t];
      bvn[t] = s + bn[t];
    }
  }
}

// ---------------- fused groupnorm: bf16 LDS stage (33KB -> 4 blocks/CU), fp8 outputs ----
__global__ __launch_bounds__(256) void gn_fused(const float* __restrict__ x,
                                                u8* __restrict__ Hn8,
                                                u8* __restrict__ HnT8) {
  __shared__ u16 lds2[16 * 1032];
  __shared__ float red[10];
  const int bg = blockIdx.x, b = bg >> 5, g = bg & 31;
  const int t = threadIdx.x;
  const float4* p4 = (const float4*)(x + (size_t)bg * 16384);
  float s = 0.f, s2 = 0.f;
  for (int i = t; i < 4096; i += 256) {
    const float4 v = p4[i];
    const int e = i * 4, ic = e >> 10, n = e & 1023;
    ushort4 sv;
    sv.x = f2bf(v.x); sv.y = f2bf(v.y); sv.z = f2bf(v.z); sv.w = f2bf(v.w);
    *(ushort4*)(lds2 + ic * 1032 + n) = sv;
    s  += v.x + v.y + v.z + v.w;
    s2 += v.x * v.x + v.y * v.y + v.z * v.z + v.w * v.w;
  }
#pragma unroll
  for (int o = 32; o; o >>= 1) { s += __shfl_xor(s, o); s2 += __shfl_xor(s2, o); }
  const int lane = t & 63, w = t >> 6;
  if (lane == 0) { red[w] = s; red[4 + w] = s2; }
  __syncthreads();
  if (t == 0) {
    s  = red[0] + red[1] + red[2] + red[3];
    s2 = red[4] + red[5] + red[6] + red[7];
    const float inv = 1.0f / 16384.0f;
    const float mean = s * inv;
    const float var  = s2 * inv - mean * mean;
    red[8] = mean;
    red[9] = rsqrtf(var + kEps);
  }
  __syncthreads();
  const float mean = red[8], rstd = red[9];
#pragma unroll
  for (int r = 0; r < 4; ++r) {
    const int n = t + 256 * r;
    float vals[16];
#pragma unroll
    for (int ic = 0; ic < 16; ++ic)
      vals[ic] = (bf2f(lds2[ic * 1032 + n]) - mean) * rstd;
    const u64 lo = (u64)(uint32_t)pk4_fp8(vals[0], vals[1], vals[2], vals[3]) |
                   ((u64)(uint32_t)pk4_fp8(vals[4], vals[5], vals[6], vals[7]) << 32);
    const u64 hi = (u64)(uint32_t)pk4_fp8(vals[8], vals[9], vals[10], vals[11]) |
                   ((u64)(uint32_t)pk4_fp8(vals[12], vals[13], vals[14], vals[15]) << 32);
    u8* rb = Hn8 + ((size_t)(b * N_ + n)) * C_;
    *(u64*)(rb + f8pos(g * 16))     = lo;
    *(u64*)(rb + f8pos(g * 16 + 8)) = hi;
  }
  // HnT8[c][n] interleaved over k=n: each thread packs 4 consecutive n
  const int nb = t * 4;
#pragma unroll
  for (int ic = 0; ic < 16; ++ic) {
    const ushort4 hv = *(const ushort4*)(lds2 + ic * 1032 + nb);
    const int wv = pk4_fp8((bf2f(hv.x) - mean) * rstd, (bf2f(hv.y) - mean) * rstd,
                           (bf2f(hv.z) - mean) * rstd, (bf2f(hv.w) - mean) * rstd);
    *(int*)(HnT8 + ((size_t)(b * C_ + g * 16 + ic)) * N_ + f8pos(nb)) = wv;
  }
}

// ---------------- light 128x128 bf16 GEMM -> fp8 interleaved weight products ----------
__global__ __launch_bounds__(256) void gemm_w128(
    const u16* __restrict__ Ab, const u16* __restrict__ Bb, u8* __restrict__ Ob) {
  __shared__ u16 Alds[128 * 64];
  __shared__ u16 Blds[128 * 64];
  const int p = blockIdx.z;
  const u16* A = Ab + (size_t)p * 262144;
  const u16* B = Bb + (size_t)p * 262144;
  u8* O = Ob + (size_t)p * 262144;
  const int m0 = blockIdx.y * 128, n0 = blockIdx.x * 128;
  const int tid = threadIdx.x, lane = tid & 63, wid = tid >> 6;
  const int wm = wid >> 1, wn = wid & 1;
  const int sr = lane >> 3, scb = (lane & 7) ^ sr;
  const u16* Ag = A + (size_t)(m0 + wid * 32 + sr) * 512 + scb * 8;
  const u16* Bg = B + (size_t)(n0 + wid * 32 + sr) * 512 + scb * 8;
  char* Al = (char*)Alds + wid * 4096;
  char* Bl = (char*)Blds + wid * 4096;
  const int arow = lane & 15, g4 = lane >> 4, rx = lane & 7;
  f32x4 acc[4][4] = {};
  for (int k = 0; k < 512; k += 64) {
#pragma unroll
    for (int g = 0; g < 4; ++g) {
      gload16(Ag + k + g * (8 * 512), Al + g * 1024);
      gload16(Bg + k + g * (8 * 512), Bl + g * 1024);
    }
    __syncthreads();
#pragma unroll
    for (int kk = 0; kk < 2; ++kk) {
      const int pc = ((kk * 4 + g4) ^ rx) * 16;
      short8 a[4], b[4];
#pragma unroll
      for (int i = 0; i < 4; ++i)
        a[i] = *(const short8*)((const char*)Alds + (wm * 64 + i * 16 + arow) * 128 + pc);
#pragma unroll
      for (int j = 0; j < 4; ++j)
        b[j] = *(const short8*)((const char*)Blds + (wn * 64 + j * 16 + arow) * 128 + pc);
#pragma unroll
      for (int i = 0; i < 4; ++i)
#pragma unroll
        for (int j = 0; j < 4; ++j)
          acc[i][j] = __builtin_amdgcn_mfma_f32_16x16x32_bf16(a[i], b[j], acc[i][j], 0, 0, 0);
    }
    __syncthreads();
  }
#pragma unroll
  for (int i = 0; i < 4; ++i) {
    const int rowg = m0 + wm * 64 + i * 16 + ((lane >> 4) * 4);   // k-axis (c)
#pragma unroll
    for (int j = 0; j < 4; ++j) {
      const int colg = n0 + wn * 64 + j * 16 + (lane & 15);       // row (d or o)
      const f32x4 v = acc[i][j];
      *(int*)(O + (size_t)colg * 512 + f8pos(rowg)) =
          pk4_fp8(v[0], v[1], v[2], v[3]);
    }
  }
}

// ================= fp8 256x256 core: K-interleaved layout, b128 fragment reads ======
#define LDA8_(D, BASE, MH)                                                      \
  _Pragma("unroll")                                                             \
  for (int i_ = 0; i_ < 4; ++i_) {                                              \
    const int rr_ = wm * 128 + (MH) * 64 + i_ * 16 + arow;                      \
    D[i_] = *(const i64x2*)((BASE) + rr_ * 64 +                                 \
                            ((g4 ^ ((rr_ >> 1) & 3)) << 4));                    \
  }
#define LDB8_(D, BASE)                                                          \
  _Pragma("unroll")                                                             \
  for (int j_ = 0; j_ < 4; ++j_) {                                              \
    const int rr_ = wn * 64 + j_ * 16 + arow;                                   \
    D[j_] = *(const i64x2*)((BASE) + rr_ * 64 +                                 \
                            ((g4 ^ ((rr_ >> 1) & 3)) << 4));                    \
  }
#define MM8_(ACC, AA, BB, H)                                                    \
  __builtin_amdgcn_s_setprio(1);                                                \
  _Pragma("unroll")                                                             \
  for (int i_ = 0; i_ < 4; ++i_)                                                \
    _Pragma("unroll")                                                           \
    for (int j_ = 0; j_ < 4; ++j_)                                              \
      ACC[i_][j_] = __builtin_amdgcn_mfma_f32_16x16x32_fp8_fp8(                 \
          AA[i_][H], BB[j_][H], ACC[i_][j_], 0, 0, 0);                          \
  __builtin_amdgcn_s_setprio(0);

__device__ __forceinline__ void gemm_core256_f8(
    const u8* __restrict__ A, const u8* __restrict__ B,
    int Ktot, int m0, int n0,
    char* Alds, char* Blds, f32x4 acc0[4][4], f32x4 acc1[4][4]) {
  const int tid = threadIdx.x, lane = tid & 63, wid = tid >> 6;
  const int wm = wid >> 2, wn = wid & 3;
  const int rl = lane >> 2;
  const int c16 = (lane & 3) ^ ((lane >> 3) & 3);   // pre-swizzled source 16B chunk
  const u8* Ag = A + (size_t)(m0 + wid * 32 + rl) * Ktot + c16 * 16;
  const u8* Bg = B + (size_t)(n0 + wid * 32 + rl) * Ktot + c16 * 16;
  char* Al = Alds + wid * 2048;
  char* Bl = Blds + wid * 2048;
  const long long r16 = (long long)16 * Ktot;
  const int arow = lane & 15, g4 = lane >> 4;
  const int nt = Ktot >> 6;

#pragma unroll
  for (int g = 0; g < 2; ++g) {
    gload16(Ag + g * r16, Al + g * 1024);
    gload16(Bg + g * r16, Bl + g * 1024);
  }
  asm volatile("s_waitcnt vmcnt(0)" ::: "memory");
  __builtin_amdgcn_s_barrier();
  i64x2 aX[4], aY[4], bX[4];
  LDA8_(aX, Alds, 0);

  for (int t = 0; t < nt; ++t) {
    const int cur = t & 1;
    const char* Ab = Alds + cur * 16384;
    const char* Bb = Blds + cur * 16384;
    const char* An = Alds + (cur ^ 1) * 16384;
    char* Aln = Al + (cur ^ 1) * 16384;
    char* Bln = Bl + (cur ^ 1) * 16384;
    const bool nx = (t + 1 < nt);
    const long long ko = (long long)(t + 1) * 64;

    // ph0: stage next-B ; read bX + aY(mh1) ; MFMA(acc0, aX.kk0, bX.kk0)
    if (nx) {
#pragma unroll
      for (int g = 0; g < 2; ++g) gload16(Bg + ko + g * r16, Bln + g * 1024);
    }
    LDB8_(bX, Bb);
    LDA8_(aY, Ab, 1);
    asm volatile("s_waitcnt lgkmcnt(4)" ::: "memory");   // bX done; aY in flight
    __builtin_amdgcn_sched_barrier(0);
    __builtin_amdgcn_s_barrier();
    MM8_(acc0, aX, bX, 0);

    // ph1: stage next-A ; MFMA(acc1, aY.kk0, bX.kk0)
    if (nx) {
#pragma unroll
      for (int g = 0; g < 2; ++g) gload16(Ag + ko + g * r16, Aln + g * 1024);
    }
    asm volatile("s_waitcnt lgkmcnt(0)" ::: "memory");   // aY done
    __builtin_amdgcn_sched_barrier(0);
    __builtin_amdgcn_s_barrier();
    MM8_(acc1, aY, bX, 0);

    // ph2: MFMA(acc0, aX.kk1, bX.kk1)
    __builtin_amdgcn_sched_barrier(0);
    __builtin_amdgcn_s_barrier();
    MM8_(acc0, aX, bX, 1);

    // ph3: boundary; prefetch next aX under MFMA(acc1, aY.kk1, bX.kk1)
    if (nx) {
      asm volatile("s_waitcnt vmcnt(0)" ::: "memory");   // own stage loads landed
    }
    __builtin_amdgcn_sched_barrier(0);
    __builtin_amdgcn_s_barrier();                        // all waves: stages landed
    if (nx) {
      LDA8_(aX, An, 0);
    }
    MM8_(acc1, aY, bX, 1);
  }
}

// coalesced copy-out of a 256x256B fp8 tile staged in SH (row stride 256B, row-XOR swz).
__device__ __forceinline__ void copy_out_tile(const char* SH, u8* O, int LDC,
                                              int m0, int n0) {
  const int tid = threadIdx.x;
#pragma unroll
  for (int it = 0; it < 8; ++it) {
    const int flat = it * 8192 + tid * 16;
    const int row = flat >> 8, col = flat & 255;
    *(int4*)(O + (size_t)(n0 + row) * LDC + m0 + col) =
        *(const int4*)(SH + row * 256 + (col ^ ((row & 15) << 4)));
  }
}

// HWq8[n][d] = fp8(Hn·Wqk + wkbq), interleaved over d. A=WqkT8 rows d, B=Hn8 rows n.
__global__ __launch_bounds__(512, 2) void gemm_hwq_f8(
    const u8* __restrict__ Wqk8, const u8* __restrict__ Hn8,
    const float* __restrict__ wkbq, u8* __restrict__ HWq8) {
  __shared__ char SH[4 * 256 * 64];    // core: A | B halves; epilogue: 256x256B tile
  const uint3 bid = remap_xcd();
  const int z = bid.z;
  const u8* B = Hn8 + (size_t)z * ((size_t)N_ * C_);
  u8* O = HWq8 + (size_t)z * ((size_t)N_ * C_);
  const int m0 = bid.y * 256, n0 = bid.x * 256;   // m0: d, n0: n
  f32x4 acc0[4][4] = {};
  f32x4 acc1[4][4] = {};
  gemm_core256_f8(Wqk8, B, 512, m0, n0, SH, SH + 32768, acc0, acc1);

  const int lane = threadIdx.x & 63, wid = threadIdx.x >> 6;
  const int wm = wid >> 2, wn = wid & 3;
  __syncthreads();
#pragma unroll
  for (int i = 0; i < 8; ++i) {
    const int ml = wm * 128 + i * 16 + ((lane >> 4) * 4);          // d local
    const float4 bv = *(const float4*)(wkbq + m0 + ml);
    const int fp = f8pos(ml);
#pragma unroll
    for (int j = 0; j < 4; ++j) {
      const int nl = wn * 64 + j * 16 + (lane & 15);               // n local
      const f32x4 v = (i < 4) ? acc0[i][j] : acc1[i - 4][j];
      *(int*)(SH + nl * 256 + (fp ^ ((nl & 15) << 4))) =
          pk4_fp8(v[0] + bv.x, v[1] + bv.y, v[2] + bv.z, v[3] + bv.w);
    }
  }
  __syncthreads();
  copy_out_tile(SH, O, 512, m0, n0);
}

// S + exp2 epilogue: A=Hn8 rows m, B=HWq8 rows n, K=512.
__global__ __launch_bounds__(512, 2) void gemm_s_f8(
    const u8* __restrict__ Hn8, const u8* __restrict__ HWq8,
    u8* __restrict__ P8, float* __restrict__ Psum) {
  __shared__ char SH[4 * 256 * 64];
  const uint3 bid = remap_xcd();
  const int z = bid.z;
  const u8* A = Hn8  + (size_t)z * ((size_t)N_ * C_);
  const u8* B = HWq8 + (size_t)z * ((size_t)N_ * C_);
  u8*       O = P8   + (size_t)z * ((size_t)N_ * N_);
  const int m0 = bid.y * 256, n0 = bid.x * 256;
  f32x4 acc0[4][4] = {};
  f32x4 acc1[4][4] = {};
  gemm_core256_f8(A, B, 512, m0, n0, SH, SH + 32768, acc0, acc1);

  const int lane = threadIdx.x & 63, wid = threadIdx.x >> 6;
  const int wm = wid >> 2, wn = wid & 3;
  float psum[4] = {0.f, 0.f, 0.f, 0.f};
  __syncthreads();
#pragma unroll
  for (int i = 0; i < 8; ++i) {
    const int ml = wm * 128 + i * 16 + ((lane >> 4) * 4);          // m local
    const int fp = f8pos(ml);
#pragma unroll
    for (int j = 0; j < 4; ++j) {
      const int nl = wn * 64 + j * 16 + (lane & 15);               // n local
      const f32x4 v = (i < 4) ? acc0[i][j] : acc1[i - 4][j];
      const float p0 = __builtin_exp2f(v[0] * kLog2Scale) * 0.0625f;
      const float p1 = __builtin_exp2f(v[1] * kLog2Scale) * 0.0625f;
      const float p2 = __builtin_exp2f(v[2] * kLog2Scale) * 0.0625f;
      const float p3 = __builtin_exp2f(v[3] * kLog2Scale) * 0.0625f;
      psum[j] += (p0 + p1) + (p2 + p3);
      *(int*)(SH + nl * 256 + (fp ^ ((nl & 15) << 4))) = pk4_fp8(p0, p1, p2, p3);
    }
  }
  const int slot = (m0 >> 7) + wm;             // 0..7, one wave per slot
  float* Ps = Psum + ((size_t)z * 8 + slot) * N_;
#pragma unroll
  for (int j = 0; j < 4; ++j) {
    float r = psum[j];
    r += __shfl_xor(r, 16);
    r += __shfl_xor(r, 32);
    if (lane < 16) Ps[n0 + wn * 64 + j * 16 + lane] = r;
  }
  __syncthreads();
  copy_out_tile(SH, O, 1024, m0, n0);
}

// ===== fused PV + final: per block (z, 128-n-tile):
//   phase A (PV): H2[n:128][c:512] = softmax-row(P8)·Hn  -> swizzled LDS tile
//   phase B (final): out[o][n] = x + H2·WvWn + bvn  (A-frags from H2-LDS, B direct L2)
__global__ __launch_bounds__(512, 1) void gemm_pvf_f8(
    const u8* __restrict__ HnT8, const u8* __restrict__ P8,
    const float* __restrict__ Psum, const u8* __restrict__ Wvn8,
    const float* __restrict__ x, const float* __restrict__ bvn,
    float* __restrict__ Out) {
  __shared__ char SH[147456];   // [0,64K) A dbuf 2x32K; [64K,80K) B dbuf 2x8K; [80K,144K) H2
  char* Abuf = SH;
  char* Bbuf = SH + 65536;
  char* H2   = SH + 81920;      // 128 rows x 512B, chunk-swizzled
  const uint3 bid = remap_xcd();
  const int z = bid.z;
  const u8* A = HnT8 + (size_t)z * ((size_t)N_ * C_);   // rows c (512), ld 1024
  const u8* B = P8   + (size_t)z * ((size_t)N_ * N_);   // rows n, ld 1024
  const int n0 = bid.x * 128;
  const int tid = threadIdx.x, lane = tid & 63, wid = tid >> 6;
  const int wm = wid >> 1, wn = wid & 1;                // PV: 4M(c) x 2N(n)
  const int rl = lane >> 2;
  const int c16 = (lane & 3) ^ ((lane >> 3) & 3);
  const u8* Ag = A + (size_t)(wid * 64 + rl) * 1024 + c16 * 16;
  const u8* Bg = B + (size_t)(n0 + wid * 16 + rl) * 1024 + c16 * 16;
  const int arow = lane & 15, g4 = lane >> 4;
  f32x4 acc0[4][4] = {};
  f32x4 acc1[4][4] = {};

  // prologue: stage tile 0 (A: 4 gloads of 16 rows; B: 1 gload)
#pragma unroll
  for (int g = 0; g < 4; ++g)
    gload16(Ag + (size_t)g * (16 * 1024), Abuf + wid * 4096 + g * 1024);
  gload16(Bg, Bbuf + wid * 1024);
  asm volatile("s_waitcnt vmcnt(0)" ::: "memory");
  __builtin_amdgcn_s_barrier();
  i64x2 aX[4], aY[4], bX[4];
  LDA8_(aX, Abuf, 0);

  for (int t = 0; t < 16; ++t) {
    const int cur = t & 1;
    const char* Ab = Abuf + cur * 32768;
    const char* Bb = Bbuf + cur * 8192;
    const char* An = Abuf + (cur ^ 1) * 32768;
    const bool nx = (t + 1 < 16);
    const long long ko = (long long)(t + 1) * 64;

    // ph0: stage next-B(1) ; read bX + aY(mh1) ; MFMA kk0 mh0
    if (nx) gload16(Bg + ko, Bbuf + (cur ^ 1) * 8192 + wid * 1024);
    LDB8_(bX, Bb);
    LDA8_(aY, Ab, 1);
    asm volatile("s_waitcnt lgkmcnt(4)" ::: "memory");
    __builtin_amdgcn_sched_barrier(0);
    __builtin_amdgcn_s_barrier();
    MM8_(acc0, aX, bX, 0);

    // ph1: stage next-A(4) ; MFMA kk0 mh1
    if (nx) {
#pragma unroll
      for (int g = 0; g < 4; ++g)
        gload16(Ag + ko + (size_t)g * (16 * 1024),
                Abuf + (cur ^ 1) * 32768 + wid * 4096 + g * 1024);
    }
    asm volatile("s_waitcnt lgkmcnt(0)" ::: "memory");
    __builtin_amdgcn_sched_barrier(0);
    __builtin_amdgcn_s_barrier();
    MM8_(acc1, aY, bX, 0);

    // ph2: MFMA kk1 mh0
    __builtin_amdgcn_sched_barrier(0);
    __builtin_amdgcn_s_barrier();
    MM8_(acc0, aX, bX, 1);

    // ph3: boundary; next aX under MFMA kk1 mh1
    if (nx) {
      asm volatile("s_waitcnt vmcnt(0)" ::: "memory");
    }
    __builtin_amdgcn_sched_barrier(0);
    __builtin_amdgcn_s_barrier();
    if (nx) {
      LDA8_(aX, An, 0);
    }
    MM8_(acc1, aY, bX, 1);
  }

  // --- PV epilogue: normalize, store H2 tile to LDS (chunk-swizzled) ---
  const float* Ps = Psum + (size_t)z * 8 * N_;
  float inv[4];
#pragma unroll
  for (int j = 0; j < 4; ++j) {
    const int ng = n0 + wn * 64 + j * 16 + (lane & 15);
    float s = 0.f;
#pragma unroll
    for (int k = 0; k < 8; ++k) s += Ps[k * N_ + ng];
    inv[j] = 1.0f / s;
  }
#pragma unroll
  for (int i = 0; i < 8; ++i) {
    const int c = wm * 128 + i * 16 + ((lane >> 4) * 4);           // c in [0,512)
    const int fp = f8pos(c);
    const int ck = fp >> 4, sub = fp & 15;
#pragma unroll
    for (int j = 0; j < 4; ++j) {
      const int nl = wn * 64 + j * 16 + (lane & 15);               // n local [0,128)
      const f32x4 v = (i < 4) ? acc0[i][j] : acc1[i - 4][j];
      *(int*)(H2 + nl * 512 + ((ck ^ (nl & 15)) << 4) + sub) =
          pk4_fp8(v[0] * inv[j], v[1] * inv[j], v[2] * inv[j], v[3] * inv[j]);
    }
  }
  __syncthreads();

  // --- final phase: out[o][n] = x + H2·WvWn + bvn; A=H2(LDS rows n), B=Wvn8(L2 rows o)
  const int wmf = wid >> 2, wnf = wid & 3;   // 2M(n) x 4N(o)
  f32x4 acc2[4][8] = {};
#pragma unroll
  for (int t = 0; t < 8; ++t) {
    i64x2 a2[4], b2[8];
#pragma unroll
    for (int i = 0; i < 4; ++i) {
      const int rn = wmf * 64 + i * 16 + arow;
      a2[i] = *(const i64x2*)(H2 + rn * 512 + (((t * 4 + g4) ^ (rn & 15)) << 4));
    }
#pragma unroll
    for (int j = 0; j < 8; ++j) {
      const int ro = wnf * 128 + j * 16 + arow;
      b2[j] = *(const i64x2*)(Wvn8 + (size_t)ro * 512 + t * 64 + g4 * 16);
    }
#pragma unroll
    for (int i = 0; i < 4; ++i)
#pragma unroll
      for (int j = 0; j < 8; ++j)
        acc2[i][j] = __builtin_amdgcn_mfma_f32_16x16x32_fp8_fp8(
            a2[i][0], b2[j][0], acc2[i][j], 0, 0, 0);
#pragma unroll
    for (int i = 0; i < 4; ++i)
#pragma unroll
      for (int j = 0; j < 8; ++j)
        acc2[i][j] = __builtin_amdgcn_mfma_f32_16x16x32_fp8_fp8(
            a2[i][1], b2[j][1], acc2[i][j], 0, 0, 0);
  }

  const float* xb = x + (size_t)z * ((size_t)C_ * N_);
  float* Ob = Out + (size_t)z * ((size_t)C_ * N_);
#pragma unroll
  for (int i = 0; i < 4; ++i) {
    const int rown = n0 + wmf * 64 + i * 16 + ((lane >> 4) * 4);   // n global
#pragma unroll
    for (int j = 0; j < 8; ++j) {
      const int colo = wnf * 128 + j * 16 + (lane & 15);           // o in [0,512)
      const float bc = bvn[colo];
      const size_t off = (size_t)colo * N_ + rown;
      const float4 xv = *(const float4*)(xb + off);
      const f32x4 v = acc2[i][j];
      float4 ov;
      ov.x = xv.x + v[0] + bc;
      ov.y = xv.y + v[1] + bc;
      ov.z = xv.z + v[2] + bc;
      ov.w = xv.w + v[3] + bc;
      *(float4*)(Ob + off) = ov;
    }
  }
}

__global__ void sentinel_kernel(float* out, int n, float v) {
  const int i = blockIdx.x * blockDim.x + threadIdx.x;
  if (i < n) out[i] = v;
}

extern "C" void kernel_launch(void* const* d_in, const int* in_sizes, int n_in,
                              void* d_out, int out_size, void* d_ws, size_t ws_size,
                              hipStream_t stream) {
  const float* x  = (const float*)d_in[0];
  const float* Wq = (const float*)d_in[1];
  const float* bq = (const float*)d_in[2];
  const float* Wk = (const float*)d_in[3];
  // d_in[4] = bk: drops exactly (softmax shift-invariance over the m axis)
  const float* Wv = (const float*)d_in[5];
  const float* bv = (const float*)d_in[6];
  const float* Wn = (const float*)d_in[7];
  const float* bn = (const float*)d_in[8];
  float* out = (float*)d_out;

  char* ws = (char*)d_ws;
  size_t off = 0;
  u16* Wab = (u16*)(ws + off); off += (size_t)2 * 262144 * 2;  // bf16: Wq | Wv
  u16* Wbb = (u16*)(ws + off); off += (size_t)2 * 262144 * 2;  // bf16: Wk | WnT
  u8*  W8  = (u8*)(ws + off);  off += (size_t)2 * 262144;      // fp8: WqkT8 | WvWnT8
  float* wkbq = (float*)(ws + off); off += 512 * 4;
  float* bvn  = (float*)(ws + off); off += 512 * 4;
  const size_t bnc = (size_t)B_ * N_ * C_;
  u8* Hn8  = (u8*)(ws + off); off += bnc;               // fp8 [b][n][c] interleaved
  u8* HnT8 = (u8*)(ws + off); off += bnc;               // fp8 [b][c][n] interleaved
  u8* HWq8 = (u8*)(ws + off); off += bnc;               // fp8 [b][n][d] interleaved
  u8* P8   = (u8*)(ws + off); off += (size_t)B_ * N_ * N_;  // fp8 [b][n][m] interleaved
  float* Psum = (float*)(ws + off); off += (size_t)B_ * 8 * N_ * 4;

  if (ws_size < off) {
    const float v = 1.0e6f + (float)(ws_size >> 20);   // absmax ~ 1e6+MB -> diagnosable
    sentinel_kernel<<<(out_size + 255) / 256, 256, 0, stream>>>(out, out_size, v);
    return;
  }

  // merged weight prep (converts + transpose + bias vectors)
  prep_kernel<<<836, 256, 0, stream>>>(Wq, Wk, Wv, Wn, bq, bv, bn,
                                       Wab, Wbb, wkbq, bvn);
  // groupnorm -> fp8 interleaved Hn8 / HnT8
  gn_fused<<<B_ * G_, 256, 0, stream>>>(x, Hn8, HnT8);
  // weight products -> fp8 interleaved
  gemm_w128<<<dim3(4, 4, 2), 256, 0, stream>>>(Wab, Wbb, W8);
  // HWq8[n][d] = fp8(Hn·Wqk + wkbq)
  gemm_hwq_f8<<<dim3(4, 2, B_), 512, 0, stream>>>(W8, Hn8, wkbq, HWq8);
  // P8[n][m] = fp8(exp2(scale·(HWq[n]·Hn[m]))/16) + partial row-sums
  gemm_s_f8<<<dim3(4, 4, B_), 512, 0, stream>>>(Hn8, HWq8, P8, Psum);
  // fused PV + final: out = x + (softmax(P)·Hn)·WvWn + bvn
  gemm_pvf_f8<<<dim3(8, 1, B_), 512, 0, stream>>>(HnT8, P8, Psum, W8 + 262144, x, bvn, out);
}